// Round 7
// baseline (248.023 us; speedup 1.0000x reference)
//
#include <hip/hip_runtime.h>
#include <math.h>

static constexpr float kSigma2 = 0.05f * 0.05f;
static constexpr int kCap2 = 2560;  // max edges per 64-node bucket in fused LDS sort

__device__ __forceinline__ int load_idx(const void* ei, long long j, int is64) {
    if (is64) return (int)(((const long long*)ei)[j]);
    return ((const int*)ei)[j];
}

// Detect whether edge_index is int64 (all odd int32 words zero) or int32.
// (standalone version kept for the fallback path)
__global__ void k_detect(const int* __restrict__ ei32, int E, int* __restrict__ nz) {
    int t = threadIdx.x;
    int lim = E < 2048 ? E : 2048;
    int acc = 0;
    for (int k = t; k < lim; k += blockDim.x) acc |= ei32[2 * k + 1];
    if (acc) atomicOr(nz, 1);
}

// Pack points into one interleaved float4 array: pt[2n]=src_n, pt[2n+1]=tgt_n
// (both gathers for an edge hit ONE 64B line). Block 0 also runs the int64
// detection (fused to drop a whole-GPU-idle launch).
__global__ void k_pack(const float* __restrict__ src, const float* __restrict__ tgt,
                       float4* __restrict__ pt, int N,
                       const int* __restrict__ ei32, int E, int* __restrict__ nz) {
    int t = threadIdx.x;
    if (blockIdx.x == 0) {
        int lim = E < 2048 ? E : 2048;
        int acc = 0;
        for (int k = t; k < lim; k += 256) acc |= ei32[2 * k + 1];
        if (acc) atomicOr(nz, 1);
    }
    int i = blockIdx.x * blockDim.x + t;
    if (i >= N) return;
    pt[2 * i] = make_float4(src[3 * i + 0], src[3 * i + 1], src[3 * i + 2], 0.0f);
    pt[2 * i + 1] = make_float4(tgt[3 * i + 0], tgt[3 * i + 1], tgt[3 * i + 2], 0.0f);
}

// ---------------- shared Kabsch core (fp64, Jacobi on M^T M) ----------------
__device__ void kabsch_from_M(const double M[3][3], double Rm[3][3]) {
    Rm[0][0] = 1; Rm[0][1] = 0; Rm[0][2] = 0;
    Rm[1][0] = 0; Rm[1][1] = 1; Rm[1][2] = 0;
    Rm[2][0] = 0; Rm[2][1] = 0; Rm[2][2] = 1;

    double frob2 = 0.0;
#pragma unroll
    for (int r = 0; r < 3; ++r)
#pragma unroll
        for (int c = 0; c < 3; ++c) frob2 += M[r][c] * M[r][c];
    if (frob2 <= 1e-80) return;

    double A[3][3];
#pragma unroll
    for (int r = 0; r < 3; ++r)
#pragma unroll
        for (int c = 0; c < 3; ++c) {
            double s = 0.0;
#pragma unroll
            for (int k = 0; k < 3; ++k) s += M[k][r] * M[k][c];
            A[r][c] = s;
        }
    double V[3][3] = {{1, 0, 0}, {0, 1, 0}, {0, 0, 1}};
    const int PL[3] = {0, 0, 1};
    const int QL[3] = {1, 2, 2};
    // trace(A) == frob2; Jacobi converges quadratically, so a relative break
    // at 1e-14*frob2 stops after ~4-5 sweeps (was: always 15 full sweeps).
    double thr = 1e-14 * frob2;
    for (int sweep = 0; sweep < 15; ++sweep) {
        double off = fabs(A[0][1]) + fabs(A[0][2]) + fabs(A[1][2]);
        if (off <= thr) break;
        for (int pi = 0; pi < 3; ++pi) {
            int p = PL[pi], q = QL[pi], r3 = 3 - p - q;
            double apq = A[p][q];
            if (apq == 0.0) continue;
            double theta = (A[q][q] - A[p][p]) / (2.0 * apq);
            double t = copysign(1.0, theta) / (fabs(theta) + sqrt(theta * theta + 1.0));
            double c = 1.0 / sqrt(t * t + 1.0);
            double s = t * c;
            A[p][p] -= t * apq;
            A[q][q] += t * apq;
            A[p][q] = 0.0; A[q][p] = 0.0;
            double arp = A[r3][p], arq = A[r3][q];
            A[r3][p] = c * arp - s * arq; A[p][r3] = A[r3][p];
            A[r3][q] = s * arp + c * arq; A[q][r3] = A[r3][q];
#pragma unroll
            for (int k = 0; k < 3; ++k) {
                double vp = V[k][p], vq = V[k][q];
                V[k][p] = c * vp - s * vq;
                V[k][q] = s * vp + c * vq;
            }
        }
    }
    double lam[3] = {A[0][0], A[1][1], A[2][2]};
    int id0 = 0, id1 = 1, id2 = 2, tt;
    if (lam[id0] < lam[id1]) { tt = id0; id0 = id1; id1 = tt; }
    if (lam[id0] < lam[id2]) { tt = id0; id0 = id2; id2 = tt; }
    if (lam[id1] < lam[id2]) { tt = id1; id1 = id2; id2 = tt; }
    double v1[3] = {V[0][id0], V[1][id0], V[2][id0]};
    double v2[3] = {V[0][id1], V[1][id1], V[2][id1]};
    double v3[3] = {V[0][id2], V[1][id2], V[2][id2]};

    double b1[3], b2[3];
#pragma unroll
    for (int r = 0; r < 3; ++r) {
        b1[r] = M[r][0] * v1[0] + M[r][1] * v1[1] + M[r][2] * v1[2];
        b2[r] = M[r][0] * v2[0] + M[r][1] * v2[1] + M[r][2] * v2[2];
    }
    double n1 = sqrt(b1[0] * b1[0] + b1[1] * b1[1] + b1[2] * b1[2]);
    if (n1 <= 1e-150) return;
    double u1[3] = {b1[0] / n1, b1[1] / n1, b1[2] / n1};
    double dot = u1[0] * b2[0] + u1[1] * b2[1] + u1[2] * b2[2];
    double w2[3] = {b2[0] - dot * u1[0], b2[1] - dot * u1[1], b2[2] - dot * u1[2]};
    double n2 = sqrt(w2[0] * w2[0] + w2[1] * w2[1] + w2[2] * w2[2]);
    double u2[3];
    if (n2 > n1 * 1e-12) {
        u2[0] = w2[0] / n2; u2[1] = w2[1] / n2; u2[2] = w2[2] / n2;
    } else {
        double ex0 = (fabs(u1[0]) < 0.9) ? 1.0 : 0.0;
        double ex1 = 1.0 - ex0;
        double cx = u1[1] * 0.0 - u1[2] * ex1;
        double cy = u1[2] * ex0 - u1[0] * 0.0;
        double cz = u1[0] * ex1 - u1[1] * ex0;
        double cn = sqrt(cx * cx + cy * cy + cz * cz);
        u2[0] = cx / cn; u2[1] = cy / cn; u2[2] = cz / cn;
    }
    double u3[3] = {u1[1] * u2[2] - u1[2] * u2[1],
                    u1[2] * u2[0] - u1[0] * u2[2],
                    u1[0] * u2[1] - u1[1] * u2[0]};
    double dV = v1[0] * (v2[1] * v3[2] - v2[2] * v3[1])
              - v1[1] * (v2[0] * v3[2] - v2[2] * v3[0])
              + v1[2] * (v2[0] * v3[1] - v2[1] * v3[0]);
    dV = (dV >= 0.0) ? 1.0 : -1.0;
#pragma unroll
    for (int r = 0; r < 3; ++r)
#pragma unroll
        for (int c = 0; c < 3; ++c)
            Rm[r][c] = u1[r] * v1[c] + u2[r] * v2[c] + dV * u3[r] * v3[c];
}

// ---------------- bucketed counting-sort path ----------------
// fine bucket = dst >> 6 (64 nodes). final payload: x = (nbr<<6)|(dst&63), y = w bits.
// coarse bucket = dst >> 13 (128 fine buckets). intermediate payload:
//   x = (nbr<<13)|(dst&8191), y = w bits.
//
// Measured (r1/r2): global atomic RMWs cost per-TRANSACTION (~32B memory-side
// write each; WRITE_SIZE == 32B x atomic count, invariant to address
// grouping). The histogram and both scatters therefore use (near-)zero global
// atomics: per-tile histograms are written non-atomically and reduced by
// k_bsum; coarse scatter bases come from an exact prefix (ccnt->cscan->cbase).

// 4096 edges per block, 782 blocks. Non-atomic thist row; ccnt derived from
// the LDS histogram by 16-lane reduction (no per-edge ballots).
__global__ void __launch_bounds__(256) k_bhist(const void* __restrict__ ei,
                                               int* __restrict__ thist,
                                               int* __restrict__ ccnt,
                                               const int* __restrict__ nz,
                                               int E, int N, int nbuckets,
                                               int ntiles4) {
    __shared__ int lhist[2048];
    int t = threadIdx.x;
    long long tile = (long long)blockIdx.x * 4096;
    long long remll = (long long)E - tile;
    int rem = (remll < 4096) ? (int)remll : 4096;
    int is64 = (*nz == 0);
    for (int i = t; i < 2048; i += 256) lhist[i] = 0;
    __syncthreads();
    if (rem == 4096) {
        for (int it = 0; it < 2; ++it) {
            long long base = tile + (long long)it * 2048 + (long long)t * 8;
            int d[8];
            if (is64) {
                const long long* p = (const long long*)ei + base;
#pragma unroll
                for (int k = 0; k < 4; ++k) {
                    longlong2 v = ((const longlong2*)p)[k];
                    d[2 * k] = (int)v.x;
                    d[2 * k + 1] = (int)v.y;
                }
            } else {
                const int* p = (const int*)ei + base;
                int4 a = ((const int4*)p)[0];
                int4 bb = ((const int4*)p)[1];
                d[0] = a.x; d[1] = a.y; d[2] = a.z; d[3] = a.w;
                d[4] = bb.x; d[5] = bb.y; d[6] = bb.z; d[7] = bb.w;
            }
#pragma unroll
            for (int k = 0; k < 8; ++k)
                if ((unsigned)d[k] < (unsigned)N) atomicAdd(&lhist[d[k] >> 6], 1);
        }
    } else {
        for (int idx = t; idx < rem; idx += 256) {
            int dk = load_idx(ei, tile + idx, is64);
            if ((unsigned)dk < (unsigned)N) atomicAdd(&lhist[dk >> 6], 1);
        }
    }
    __syncthreads();
    // non-atomic per-tile histogram row: 8KB coalesced store.
    int* row = thist + (long long)blockIdx.x * 2048;
    for (int b = t; b < 2048; b += 256) row[b] = lhist[b];
    // per-tile coarse counts: thread t sums bins t*8..t*8+7, 16-lane reduce.
    int part = 0;
#pragma unroll
    for (int j = 0; j < 8; ++j) part += lhist[t * 8 + j];
#pragma unroll
    for (int off = 8; off >= 1; off >>= 1) part += __shfl_down(part, off, 16);
    if ((t & 15) == 0) ccnt[(long long)blockIdx.x * 16 + (t >> 4)] = part;
}

// Reduce thist over tiles -> btot[bin]. 128 blocks x 16 bins; L2-resident.
__global__ void __launch_bounds__(256) k_bsum(const int* __restrict__ thist,
                                              int* __restrict__ btot, int ntiles) {
    int t = threadIdx.x;
    int bin = blockIdx.x * 16 + (t >> 4);
    int j = t & 15;
    int s = 0;
    for (int i = j; i < ntiles; i += 16) s += thist[(long long)i * 2048 + bin];
#pragma unroll
    for (int off = 8; off >= 1; off >>= 1) s += __shfl_down(s, off, 16);
    if (j == 0) btot[bin] = s;
}

// fine exclusive scan (up to 2048 bins, 1024 thr x 2) -> boff, cur16.
// FUSED cscan phase: 16 waves then scan ccnt over tiles per coarse bin via
// 64-lane shuffle scans (no barriers in the chunk loop) -> cbase.
__global__ void k_scan(const int* __restrict__ btot, int* __restrict__ boff,
                       int* __restrict__ cur16,
                       const int* __restrict__ ccnt, int* __restrict__ cbase,
                       int nbuckets, int ntiles, int ncoarse) {
    __shared__ int sm[2048];
    __shared__ int exco[17];
    int t = threadIdx.x;
    int v0 = (t < nbuckets) ? btot[t] : 0;
    int v1 = (t + 1024 < nbuckets) ? btot[t + 1024] : 0;
    sm[t] = v0;
    sm[t + 1024] = v1;
    __syncthreads();
    for (int s = 1; s < 2048; s <<= 1) {
        int x0 = (t >= s) ? sm[t - s] : 0;
        int x1 = (t + 1024 >= s) ? sm[t + 1024 - s] : 0;
        __syncthreads();
        sm[t] += x0;
        sm[t + 1024] += x1;
        __syncthreads();
    }
    if (t < nbuckets) {
        int ex = sm[t] - v0;
        boff[t] = ex;
        cur16[t * 16] = ex;
        if ((t & 127) == 0) exco[t >> 7] = ex;
    }
    int t2 = t + 1024;
    if (t2 < nbuckets) {
        int ex = sm[t2] - v1;
        boff[t2] = ex;
        cur16[t2 * 16] = ex;
        if ((t2 & 127) == 0) exco[t2 >> 7] = ex;
    }
    if (t == nbuckets - 1) boff[nbuckets] = sm[t];
    if (t2 == nbuckets - 1) boff[nbuckets] = sm[t2];
    __syncthreads();
    // cscan phase: wave w scans coarse bin w over all tiles.
    int w = t >> 6, l = t & 63;
    if (w < ncoarse) {
        int run = exco[w];
        for (int start = 0; start < ntiles; start += 64) {
            int i = start + l;
            int v = (i < ntiles) ? ccnt[(long long)i * 16 + w] : 0;
            int x = v;
#pragma unroll
            for (int d = 1; d < 64; d <<= 1) {
                int y = __shfl_up(x, d, 64);
                if (l >= d) x += y;
            }
            if (i < ntiles) cbase[(long long)i * 16 + w] = run + x - v;
            run += __shfl(x, 63, 64);
        }
    }
}

// Level-1 scatter: raw edges -> coarse-sorted sedge1 (<=16 bins, long runs).
// 4096-edge tiles; wave-ballot ranking; ZERO global atomics (bases come from
// the precomputed cbase prefix).
__global__ void __launch_bounds__(256) k_cscatter(const void* __restrict__ ei,
                                                  const float* __restrict__ ew,
                                                  const int* __restrict__ cbase,
                                                  int2* __restrict__ sedge1,
                                                  const int* __restrict__ nz,
                                                  int E, int N, int ncoarse) {
    __shared__ int2 stage[4096];
    __shared__ unsigned char binOf[4096];
    __shared__ int hist[16];
    __shared__ int excl[16];
    __shared__ int gbase[16];
    __shared__ int woffs[4][16];   // per-wave running bin counts
    __shared__ int wbase[4][16];   // per-wave base within bin (tile-local)
    int t = threadIdx.x;
    int w = t >> 6, lane = t & 63;
    unsigned long long lanebelow = ((unsigned long long)1 << lane) - 1;
    long long tile = (long long)blockIdx.x * 4096;
    long long remll = (long long)E - tile;
    int rem = (remll < 4096) ? (int)remll : 4096;
    int is64 = (*nz == 0);
    if (t < 16) hist[t] = 0;
    if (t < 64) ((int*)woffs)[t] = 0;
    __syncthreads();

    int mybin[16];
    int mypos[16];   // position within this wave's portion of the bin
    int2 mypay[16];
#pragma unroll
    for (int h = 0; h < 2; ++h) {
        int dd[8], nn[8];
        float ww[8];
        int cnt8 = 0;
        int coff = h * 2048 + t * 8;
        long long cb = tile + coff;
        if (coff + 8 <= rem) {
            if (is64) {
                const long long* pd = (const long long*)ei + cb;
                const long long* pn = (const long long*)ei + (long long)E + cb;
#pragma unroll
                for (int k = 0; k < 4; ++k) {
                    longlong2 vd = ((const longlong2*)pd)[k];
                    longlong2 vn = ((const longlong2*)pn)[k];
                    dd[2 * k] = (int)vd.x; dd[2 * k + 1] = (int)vd.y;
                    nn[2 * k] = (int)vn.x; nn[2 * k + 1] = (int)vn.y;
                }
            } else {
                const int* pd = (const int*)ei + cb;
                const int* pn = (const int*)ei + (long long)E + cb;
                int4 a = ((const int4*)pd)[0], b = ((const int4*)pd)[1];
                int4 c = ((const int4*)pn)[0], d = ((const int4*)pn)[1];
                dd[0] = a.x; dd[1] = a.y; dd[2] = a.z; dd[3] = a.w;
                dd[4] = b.x; dd[5] = b.y; dd[6] = b.z; dd[7] = b.w;
                nn[0] = c.x; nn[1] = c.y; nn[2] = c.z; nn[3] = c.w;
                nn[4] = d.x; nn[5] = d.y; nn[6] = d.z; nn[7] = d.w;
            }
            const float* pw = ew + cb;
            float4 wa = ((const float4*)pw)[0], wb = ((const float4*)pw)[1];
            ww[0] = wa.x; ww[1] = wa.y; ww[2] = wa.z; ww[3] = wa.w;
            ww[4] = wb.x; ww[5] = wb.y; ww[6] = wb.z; ww[7] = wb.w;
            cnt8 = 8;
        } else {
#pragma unroll
            for (int k = 0; k < 8; ++k) {
                if (coff + k < rem) {
                    dd[cnt8] = load_idx(ei, cb + k, is64);
                    nn[cnt8] = load_idx(ei, (long long)E + cb + k, is64);
                    ww[cnt8] = ew[cb + k];
                    ++cnt8;
                }
            }
        }
        // ballot-ranked binning: per round, each lane handles one edge
#pragma unroll
        for (int k = 0; k < 8; ++k) {
            int r = h * 8 + k;
            int bin = -1;
            if (k < cnt8) {
                int d = dd[k];
                if ((unsigned)d < (unsigned)N) {
                    int n = nn[k];
                    if ((unsigned)n >= (unsigned)N) n = N;  // sentinel; filtered later
                    bin = d >> 13;
                    mypay[r].x = (n << 13) | (d & 8191);
                    mypay[r].y = __float_as_int(ww[k]);
                }
            }
            mybin[r] = bin;
            unsigned long long valid = __ballot(bin >= 0);
            unsigned long long v0 = __ballot(bin & 1);
            unsigned long long v1 = __ballot(bin & 2);
            unsigned long long v2 = __ballot(bin & 4);
            unsigned long long v3 = __ballot(bin & 8);
            if (bin >= 0) {
                unsigned long long m = valid;
                m &= (bin & 1) ? v0 : ~v0;
                m &= (bin & 2) ? v1 : ~v1;
                m &= (bin & 4) ? v2 : ~v2;
                m &= (bin & 8) ? v3 : ~v3;
                int rank = __popcll(m & lanebelow);
                int cnt = __popcll(m);
                int cur = woffs[w][bin];
                mypos[r] = cur + rank;
                if (rank == 0) woffs[w][bin] = cur + cnt;
            }
        }
    }
    __syncthreads();
    // cross-wave bases: 64 LDS atomics
    if (t < 64) {
        int w2 = t >> 4, b = t & 15;
        int c = woffs[w2][b];
        wbase[w2][b] = (c > 0) ? atomicAdd(&hist[b], c) : 0;
    }
    __syncthreads();
    if (t == 0) {
        int run = 0;
#pragma unroll
        for (int c = 0; c < 16; ++c) { excl[c] = run; run += hist[c]; }
    }
    __syncthreads();
#pragma unroll
    for (int r = 0; r < 16; ++r) {
        if (mybin[r] >= 0) {
            int lpos = excl[mybin[r]] + wbase[w][mybin[r]] + mypos[r];
            stage[lpos] = mypay[r];
            binOf[lpos] = (unsigned char)mybin[r];
        }
    }
    if (t < 16) gbase[t] = cbase[(long long)blockIdx.x * 16 + t];
    __syncthreads();
    int total = excl[15] + hist[15];
    for (int lpos = t; lpos < total; lpos += 256) {
        int c = binOf[lpos];
        sedge1[(long long)gbase[c] + (lpos - excl[c])] = stage[lpos];
    }
}

// Level-2 scatter: coarse-sorted sedge1 -> fine-sorted sedge2 (repacks payload).
// 4096-edge tiles, wave-ballot ranking over a <=256-bin window (tile spans at
// most 2 coarse bins with uniform data; wider spans take the rare slow path).
// Per-bin runs are ~32 edges = 256B coalesced writes.
__global__ void __launch_bounds__(256) k_fscatter(const int2* __restrict__ sedge1,
                                                  int* __restrict__ cur16,
                                                  const int* __restrict__ boff,
                                                  int2* __restrict__ sedge2,
                                                  int E, int nbuckets, int ncoarse) {
    __shared__ int2 stage[4096];
    __shared__ unsigned short binOf[4096];
    __shared__ int hist[256];
    __shared__ int lincl[256];
    __shared__ int gbase[256];
    __shared__ int woffs[4][256];   // per-wave running bin counts
    __shared__ int wbase[4][256];   // per-wave base within bin (tile-local)
    __shared__ int co[17];
    __shared__ int s_clo, s_W;
    int t = threadIdx.x;
    int w = t >> 6, lane = t & 63;
    unsigned long long lanebelow = ((unsigned long long)1 << lane) - 1;
    if (t <= ncoarse) {
        int f = t * 128;
        if (f > nbuckets) f = nbuckets;
        co[t] = boff[f];
    }
    __syncthreads();
    int Ev = co[ncoarse];
    long long tile = (long long)blockIdx.x * 4096;
    if (tile >= Ev) return;
    long long remll = (long long)Ev - tile;
    int rem = (remll < 4096) ? (int)remll : 4096;

    if (t == 0) {
        long long p0 = tile, p1 = tile + rem - 1;
        int c0 = 0;
        while (c0 + 1 < ncoarse && p0 >= co[c0 + 1]) ++c0;
        int c1 = c0;
        while (c1 + 1 < ncoarse && p1 >= co[c1 + 1]) ++c1;
        s_clo = c0;
        s_W = (c1 - c0 + 1) * 128;
    }
    hist[t] = 0;
    for (int i = t; i < 1024; i += 256) ((int*)woffs)[i] = 0;
    __syncthreads();
    int clo = s_clo, W = s_W;

    // load 16 edges/thread (two 2048-edge halves, int4 vector loads)
    int2 pay[16];
#pragma unroll
    for (int h = 0; h < 2; ++h) {
        int coff = h * 2048 + t * 8;
        if (coff + 8 <= rem) {
            const int4* p4 = (const int4*)(sedge1 + tile + coff);
#pragma unroll
            for (int k = 0; k < 4; ++k) {
                int4 v = p4[k];
                pay[h * 8 + 2 * k].x = v.x;     pay[h * 8 + 2 * k].y = v.y;
                pay[h * 8 + 2 * k + 1].x = v.z; pay[h * 8 + 2 * k + 1].y = v.w;
            }
        } else {
#pragma unroll
            for (int k = 0; k < 8; ++k)
                if (coff + k < rem) pay[h * 8 + k] = sedge1[tile + coff + k];
        }
    }

    if (W > 256) {
        // slow path (only if a tile spans >=3 coarse bins -- requires a tiny
        // coarse bin; essentially never with uniform data)
#pragma unroll
        for (int h = 0; h < 2; ++h) {
#pragma unroll
            for (int k = 0; k < 8; ++k) {
                int coff = h * 2048 + t * 8 + k;
                if (coff < rem) {
                    long long pos = tile + coff;
                    int x1 = pay[h * 8 + k].x;
                    int c = clo;
                    while (c + 1 < ncoarse && pos >= co[c + 1]) ++c;
                    unsigned nbr = ((unsigned)x1) >> 13;
                    int fin = c * 128 + ((x1 & 8191) >> 6);
                    int gpos = atomicAdd(&cur16[fin * 16], 1);
                    int2 out;
                    out.x = (int)((nbr << 6) | (unsigned)(x1 & 63));
                    out.y = pay[h * 8 + k].y;
                    sedge2[gpos] = out;
                }
            }
        }
        return;
    }

    // ballot-ranked binning (8-bit rel): no per-edge LDS atomics
    int mybin[16];
    int mypos[16];
#pragma unroll
    for (int h = 0; h < 2; ++h) {
#pragma unroll
        for (int k = 0; k < 8; ++k) {
            int r = h * 8 + k;
            int coff = h * 2048 + t * 8 + k;
            int bin = -1;
            if (coff < rem) {
                long long pos = tile + coff;
                int x1 = pay[r].x;
                int c = clo;
                while (c + 1 < ncoarse && pos >= co[c + 1]) ++c;
                bin = (c - clo) * 128 + ((x1 & 8191) >> 6);
            }
            mybin[r] = bin;
            unsigned long long vm = __ballot(bin >= 0);
            unsigned long long b0 = __ballot(bin & 1);
            unsigned long long b1 = __ballot(bin & 2);
            unsigned long long b2 = __ballot(bin & 4);
            unsigned long long b3 = __ballot(bin & 8);
            unsigned long long b4 = __ballot(bin & 16);
            unsigned long long b5 = __ballot(bin & 32);
            unsigned long long b6 = __ballot(bin & 64);
            unsigned long long b7 = __ballot(bin & 128);
            if (bin >= 0) {
                unsigned long long m = vm;
                m &= (bin & 1) ? b0 : ~b0;
                m &= (bin & 2) ? b1 : ~b1;
                m &= (bin & 4) ? b2 : ~b2;
                m &= (bin & 8) ? b3 : ~b3;
                m &= (bin & 16) ? b4 : ~b4;
                m &= (bin & 32) ? b5 : ~b5;
                m &= (bin & 64) ? b6 : ~b6;
                m &= (bin & 128) ? b7 : ~b7;
                int rank = __popcll(m & lanebelow);
                int cnt = __popcll(m);
                int cur = woffs[w][bin];
                mypos[r] = cur + rank;
                if (rank == 0) woffs[w][bin] = cur + cnt;
            }
        }
    }
    __syncthreads();
    // cross-wave bases: thread t handles bin t across the 4 waves
    {
        int c0 = woffs[0][t], c1 = woffs[1][t], c2 = woffs[2][t], c3 = woffs[3][t];
        int run = 0;
        wbase[0][t] = run; run += c0;
        wbase[1][t] = run; run += c1;
        wbase[2][t] = run; run += c2;
        wbase[3][t] = run; run += c3;
        hist[t] = run;
    }
    __syncthreads();
    lincl[t] = hist[t];
    __syncthreads();
    for (int s = 1; s < 256; s <<= 1) {
        int x = (t >= s) ? lincl[t - s] : 0;
        __syncthreads();
        lincl[t] += x;
        __syncthreads();
    }
#pragma unroll
    for (int r = 0; r < 16; ++r) {
        if (mybin[r] >= 0) {
            int bin = mybin[r];
            int ex = lincl[bin] - hist[bin];
            int lpos = ex + wbase[w][bin] + mypos[r];
            int x1 = pay[r].x;
            unsigned nbr = ((unsigned)x1) >> 13;
            int2 out;
            out.x = (int)((nbr << 6) | (unsigned)(x1 & 63));
            out.y = pay[r].y;
            stage[lpos] = out;
            binOf[lpos] = (unsigned short)bin;
        }
    }
    {
        int c = hist[t];
        int fin = clo * 128 + t;
        gbase[t] = (c > 0 && fin < nbuckets) ? atomicAdd(&cur16[fin * 16], c) : 0;
    }
    __syncthreads();
    int total = lincl[255];
    for (int lpos = t; lpos < total; lpos += 256) {
        int rel = binOf[lpos];
        int ex = lincl[rel] - hist[rel];
        sedge2[gbase[rel] + (lpos - ex)] = stage[lpos];
    }
}

// Single-level scatter (fallback when ws can't hold two edge buffers).
__global__ void __launch_bounds__(256) k_binscatter(const void* __restrict__ ei,
                                                    const float* __restrict__ ew,
                                                    int* __restrict__ cur16,
                                                    int2* __restrict__ sedge,
                                                    const int* __restrict__ nz,
                                                    int E, int N, int nbuckets) {
    __shared__ int2 stage[2048];
    __shared__ unsigned short binOf[2048];
    __shared__ int lhist[2048];
    __shared__ int lincl[2048];
    __shared__ int gbase[2048];
    int t = threadIdx.x;
    long long tile = (long long)blockIdx.x * 2048;
    long long remll = (long long)E - tile;
    int rem = (remll < 2048) ? (int)remll : 2048;
    int is64 = (*nz == 0);
    for (int i = t; i < 2048; i += 256) lhist[i] = 0;
    __syncthreads();

    int dd[8], nn[8];
    float ww[8];
    int cnt8 = 0;
    if (rem == 2048) {
        if (is64) {
            const long long* pd = (const long long*)ei + tile + (long long)t * 8;
            const long long* pn = (const long long*)ei + (long long)E + tile + (long long)t * 8;
#pragma unroll
            for (int k = 0; k < 4; ++k) {
                longlong2 vd = ((const longlong2*)pd)[k];
                longlong2 vn = ((const longlong2*)pn)[k];
                dd[2 * k] = (int)vd.x; dd[2 * k + 1] = (int)vd.y;
                nn[2 * k] = (int)vn.x; nn[2 * k + 1] = (int)vn.y;
            }
        } else {
            const int* pd = (const int*)ei + tile + (long long)t * 8;
            const int* pn = (const int*)ei + (long long)E + tile + (long long)t * 8;
            int4 a = ((const int4*)pd)[0], b = ((const int4*)pd)[1];
            int4 c = ((const int4*)pn)[0], d = ((const int4*)pn)[1];
            dd[0] = a.x; dd[1] = a.y; dd[2] = a.z; dd[3] = a.w;
            dd[4] = b.x; dd[5] = b.y; dd[6] = b.z; dd[7] = b.w;
            nn[0] = c.x; nn[1] = c.y; nn[2] = c.z; nn[3] = c.w;
            nn[4] = d.x; nn[5] = d.y; nn[6] = d.z; nn[7] = d.w;
        }
        const float* pw = ew + tile + (long long)t * 8;
        float4 wa = ((const float4*)pw)[0], wb = ((const float4*)pw)[1];
        ww[0] = wa.x; ww[1] = wa.y; ww[2] = wa.z; ww[3] = wa.w;
        ww[4] = wb.x; ww[5] = wb.y; ww[6] = wb.z; ww[7] = wb.w;
        cnt8 = 8;
    } else {
        int base = t * 8;
#pragma unroll
        for (int k = 0; k < 8; ++k) {
            int idx = base + k;
            if (idx < rem) {
                long long e = tile + idx;
                dd[cnt8] = load_idx(ei, e, is64);
                nn[cnt8] = load_idx(ei, (long long)E + e, is64);
                ww[cnt8] = ew[e];
                ++cnt8;
            }
        }
    }

    int mybin[8];
    int myrank[8];
    int2 mypay[8];
#pragma unroll
    for (int k = 0; k < 8; ++k) {
        mybin[k] = -1;
        if (k < cnt8) {
            int d = dd[k];
            if ((unsigned)d < (unsigned)N) {
                int n = nn[k];
                if ((unsigned)n >= (unsigned)N) n = N;  // sentinel
                int bb = d >> 6;
                mybin[k] = bb;
                myrank[k] = atomicAdd(&lhist[bb], 1);
                mypay[k].x = (n << 6) | (d & 63);
                mypay[k].y = __float_as_int(ww[k]);
            }
        }
    }
    __syncthreads();
    for (int i = t; i < 2048; i += 256) lincl[i] = lhist[i];
    __syncthreads();
    for (int s = 1; s < 2048; s <<= 1) {
        int tmp[8];
#pragma unroll
        for (int j = 0; j < 8; ++j) {
            int i = (j << 8) + t;
            tmp[j] = (i >= s) ? lincl[i - s] : 0;
        }
        __syncthreads();
#pragma unroll
        for (int j = 0; j < 8; ++j) {
            int i = (j << 8) + t;
            lincl[i] += tmp[j];
        }
        __syncthreads();
    }
#pragma unroll
    for (int k = 0; k < 8; ++k) {
        if (mybin[k] >= 0) {
            int ex = lincl[mybin[k]] - lhist[mybin[k]];
            int lpos = ex + myrank[k];
            stage[lpos] = mypay[k];
            binOf[lpos] = (unsigned short)mybin[k];
        }
    }
    __syncthreads();
    for (int bb = t; bb < 2048; bb += 256) {
        int c = lhist[bb];
        gbase[bb] = (c > 0 && bb < nbuckets) ? atomicAdd(&cur16[bb * 16], c) : 0;
    }
    __syncthreads();
    int total = lincl[2047];
    for (int lpos = t; lpos < total; lpos += 256) {
        int bb = binOf[lpos];
        int ex = lincl[bb] - lhist[bb];
        sedge[gbase[bb] + (lpos - ex)] = stage[lpos];
    }
}

// 23-moment accumulate for one edge.
__device__ __forceinline__ void mom_acc(float v[23], float w_, float4 a, float4 bb) {
    float sx = a.x, sy = a.y, sz = a.z;
    float tx = bb.x, ty = bb.y, tz = bb.z;
    v[0] += 1.0f;
    v[1] += sx; v[2] += sy; v[3] += sz;
    v[4] += tx; v[5] += ty; v[6] += tz;
    v[7] += w_;
    float wsx = w_ * sx, wsy = w_ * sy, wsz = w_ * sz;
    v[8] += wsx; v[9] += wsy; v[10] += wsz;
    v[11] += w_ * tx; v[12] += w_ * ty; v[13] += w_ * tz;
    v[14] += wsx * tx; v[15] += wsx * ty; v[16] += wsx * tz;
    v[17] += wsy * tx; v[18] += wsy * ty; v[19] += wsy * tz;
    v[20] += wsz * tx; v[21] += wsz * ty; v[22] += wsz * tz;
}

// Fused per-bucket sort (64 nodes, in LDS, no write-back) + 23-moment pass.
// __launch_bounds__(256,4): allow up to 128 VGPR/wave (the prior build's
// 40-VGPR allocation serialized the gather unroll through recycled registers
// -- no MLP). Sort phase issues ALL rounds' sedge2 loads back-to-back into
// registers, then ranks (1 HBM round-trip instead of ~8 serialized ones).
__global__ void __launch_bounds__(256, 4) k_sortmoment(const int* __restrict__ boff,
                                                       const int2* __restrict__ sedge2,
                                                       const float4* __restrict__ pt,
                                                       float* __restrict__ momG, int N) {
    __shared__ int2 sorted[kCap2];
    __shared__ int hist[64];
    __shared__ int offs[64];
    __shared__ int scanbuf[64];
    __shared__ int woffs[4][64];   // per-wave per-bin counts
    __shared__ int wbase[4][64];   // per-wave exclusive base within bin
    int b = blockIdx.x, t = threadIdx.x;
    int w = t >> 6, lane = t & 63;
    unsigned long long lanebelow = ((unsigned long long)1 << lane) - 1;
    int e0 = boff[b], e1 = boff[b + 1];
    int cnt = e1 - e0;
    int inlds = (cnt <= kCap2);
    if (t < 64) hist[t] = 0;
    ((int*)woffs)[t] = 0;   // 256 threads cover all 4x64 entries
    __syncthreads();
    if (inlds) {
        int2 pay[10];
        int mypos[10];
        int nrounds = (cnt + 255) >> 8;
        // phase 1: issue all loads (independent -> all in flight)
#pragma unroll
        for (int r = 0; r < 10; ++r) {
            if (r >= nrounds) break;
            int idx = r * 256 + t;
            if (idx < cnt) pay[r] = sedge2[e0 + idx];
        }
        // phase 2: ballot ranking, register-only
#pragma unroll
        for (int r = 0; r < 10; ++r) {
            if (r >= nrounds) break;
            int idx = r * 256 + t;
            int bin = (idx < cnt) ? (pay[r].x & 63) : -1;
            unsigned long long vm = __ballot(bin >= 0);
            unsigned long long b0 = __ballot(bin & 1);
            unsigned long long b1 = __ballot(bin & 2);
            unsigned long long b2 = __ballot(bin & 4);
            unsigned long long b3 = __ballot(bin & 8);
            unsigned long long b4 = __ballot(bin & 16);
            unsigned long long b5 = __ballot(bin & 32);
            if (bin >= 0) {
                unsigned long long m = vm;
                m &= (bin & 1) ? b0 : ~b0;
                m &= (bin & 2) ? b1 : ~b1;
                m &= (bin & 4) ? b2 : ~b2;
                m &= (bin & 8) ? b3 : ~b3;
                m &= (bin & 16) ? b4 : ~b4;
                m &= (bin & 32) ? b5 : ~b5;
                int rank = __popcll(m & lanebelow);
                int cm = __popcll(m);
                int curv = woffs[w][bin];
                mypos[r] = curv + rank;
                if (rank == 0) woffs[w][bin] = curv + cm;
            }
        }
        __syncthreads();
        {   // cross-wave exclusive bases: 256 atomics, <=4 contenders/address
            int w2 = t >> 6, bb = t & 63;
            int c = woffs[w2][bb];
            wbase[w2][bb] = (c > 0) ? atomicAdd(&hist[bb], c) : 0;
        }
        __syncthreads();
        if (t < 64) scanbuf[t] = hist[t];
        __syncthreads();
        for (int s = 1; s < 64; s <<= 1) {
            int v = 0;
            if (t < 64 && t >= s) v = scanbuf[t - s];
            __syncthreads();
            if (t < 64) scanbuf[t] += v;
            __syncthreads();
        }
        if (t < 64) offs[t] = scanbuf[t] - hist[t];
        __syncthreads();
#pragma unroll
        for (int r = 0; r < 10; ++r) {
            if (r >= nrounds) break;
            int idx = r * 256 + t;
            if (idx < cnt) {
                int bin = pay[r].x & 63;
                sorted[offs[bin] + wbase[w][bin] + mypos[r]] = pay[r];
            }
        }
        __syncthreads();
    }
    int oct = t >> 3, lane8 = t & 7;
#pragma unroll
    for (int rr = 0; rr < 2; ++rr) {
        int nl = oct + rr * 32;
        long long node = (long long)b * 64 + nl;
        float v[23];
#pragma unroll
        for (int i = 0; i < 23; ++i) v[i] = 0.0f;
        if (node < N) {
            if (inlds) {
                int start = offs[nl];
                int cn = hist[nl];
                int j = lane8;
                // 4x unroll: issue all four edges' gathers before accumulating
                // (sentinel n==N reads the valid dummy slot pt[2N..2N+1]).
                for (; j + 24 < cn; j += 32) {
                    int2 p0 = sorted[start + j];
                    int2 p1 = sorted[start + j + 8];
                    int2 p2 = sorted[start + j + 16];
                    int2 p3 = sorted[start + j + 24];
                    unsigned n0 = ((unsigned)p0.x) >> 6;
                    unsigned n1 = ((unsigned)p1.x) >> 6;
                    unsigned n2 = ((unsigned)p2.x) >> 6;
                    unsigned n3 = ((unsigned)p3.x) >> 6;
                    float4 a0 = pt[2 * n0], b0v = pt[2 * n0 + 1];
                    float4 a1 = pt[2 * n1], b1v = pt[2 * n1 + 1];
                    float4 a2 = pt[2 * n2], b2v = pt[2 * n2 + 1];
                    float4 a3 = pt[2 * n3], b3v = pt[2 * n3 + 1];
                    if (n0 < (unsigned)N) mom_acc(v, __int_as_float(p0.y), a0, b0v);
                    if (n1 < (unsigned)N) mom_acc(v, __int_as_float(p1.y), a1, b1v);
                    if (n2 < (unsigned)N) mom_acc(v, __int_as_float(p2.y), a2, b2v);
                    if (n3 < (unsigned)N) mom_acc(v, __int_as_float(p3.y), a3, b3v);
                }
                for (; j + 8 < cn; j += 16) {
                    int2 p0 = sorted[start + j];
                    int2 p1 = sorted[start + j + 8];
                    unsigned n0 = ((unsigned)p0.x) >> 6;
                    unsigned n1 = ((unsigned)p1.x) >> 6;
                    float4 a0 = pt[2 * n0], b0v = pt[2 * n0 + 1];
                    float4 a1 = pt[2 * n1], b1v = pt[2 * n1 + 1];
                    if (n0 < (unsigned)N) mom_acc(v, __int_as_float(p0.y), a0, b0v);
                    if (n1 < (unsigned)N) mom_acc(v, __int_as_float(p1.y), a1, b1v);
                }
                if (j < cn) {
                    int2 p = sorted[start + j];
                    unsigned n = ((unsigned)p.x) >> 6;
                    float4 a = pt[2 * n], bb = pt[2 * n + 1];
                    if (n < (unsigned)N) mom_acc(v, __int_as_float(p.y), a, bb);
                }
            } else {
                for (int j = lane8; j < cnt; j += 8) {
                    int2 p = sedge2[e0 + j];
                    if ((p.x & 63) != nl) continue;
                    unsigned n = ((unsigned)p.x) >> 6;
                    if (n >= (unsigned)N) continue;
                    float4 a = pt[2 * n], bb = pt[2 * n + 1];
                    mom_acc(v, __int_as_float(p.y), a, bb);
                }
            }
        }
#pragma unroll
        for (int m = 1; m < 8; m <<= 1) {
#pragma unroll
            for (int i = 0; i < 23; ++i) v[i] += __shfl_xor(v[i], m, 64);
        }
        if (lane8 == 0 && node < N) {
#pragma unroll
            for (int i = 0; i < 23; ++i) momG[(size_t)i * N + node] = v[i];
        }
    }
}

// One thread per node: expand moments -> M, fp64 Kabsch, R/T/wnode.
__global__ void __launch_bounds__(256) k_kabsch2(const float* __restrict__ momG,
                                                 const float4* __restrict__ pt,
                                                 float* __restrict__ Rout,
                                                 float* __restrict__ Tout,
                                                 float* __restrict__ wnode, int N) {
    int i = blockIdx.x * blockDim.x + threadIdx.x;
    if (i >= N) return;
    float m[23];
#pragma unroll
    for (int k = 0; k < 23; ++k) m[k] = momG[(size_t)k * N + i];
    double cntv = (double)m[0];
    double inv = 1.0 / fmax(cntv, 1.0);
    double sb[3] = {m[1] * inv, m[2] * inv, m[3] * inv};
    double tb[3] = {m[4] * inv, m[5] * inv, m[6] * inv};
    double Sw = m[7];
    double Sws[3] = {m[8], m[9], m[10]};
    double Swt[3] = {m[11], m[12], m[13]};
    double M[3][3];
#pragma unroll
    for (int r = 0; r < 3; ++r)
#pragma unroll
        for (int c = 0; c < 3; ++c)
            M[r][c] = (double)m[14 + 3 * r + c]
                    - sb[r] * Swt[c] - Sws[r] * tb[c] + Sw * sb[r] * tb[c];
    double Rm[3][3];
    kabsch_from_M(M, Rm);
    double T0 = tb[0] - (Rm[0][0] * sb[0] + Rm[0][1] * sb[1] + Rm[0][2] * sb[2]);
    double T1 = tb[1] - (Rm[1][0] * sb[0] + Rm[1][1] * sb[1] + Rm[1][2] * sb[2]);
    double T2 = tb[2] - (Rm[2][0] * sb[0] + Rm[2][1] * sb[1] + Rm[2][2] * sb[2]);
#pragma unroll
    for (int r = 0; r < 3; ++r)
#pragma unroll
        for (int c = 0; c < 3; ++c)
            Rout[9 * (long long)i + 3 * r + c] = (float)Rm[r][c];
    Tout[3 * i + 0] = (float)T0;
    Tout[3 * i + 1] = (float)T1;
    Tout[3 * i + 2] = (float)T2;
    float4 a = pt[2 * i];
    float4 q = pt[2 * i + 1];
    double x0 = Rm[0][0] * a.x + Rm[0][1] * a.y + Rm[0][2] * a.z + T0;
    double x1 = Rm[1][0] * a.x + Rm[1][1] * a.y + Rm[1][2] * a.z + T1;
    double x2 = Rm[2][0] * a.x + Rm[2][1] * a.y + Rm[2][2] * a.z + T2;
    double d0 = x0 - q.x, d1 = x1 - q.y, d2 = x2 - q.z;
    double dd = d0 * d0 + d1 * d1 + d2 * d2;
    wnode[i] = (float)((double)kSigma2 / (dd + (double)kSigma2));
}

// wout[e] = wnode[nbr[e]] (8 edges/thread, vector loads, float4 stores).
__global__ void __launch_bounds__(256) k_wgather(const void* __restrict__ ei,
                                                 const float* __restrict__ wnode,
                                                 float* __restrict__ wout,
                                                 const int* __restrict__ nz,
                                                 int E, int N) {
    int gid = blockIdx.x * blockDim.x + threadIdx.x;
    long long base = (long long)gid * 8;
    if (base >= E) return;
    int is64 = (*nz == 0);
    int n_[8];
    int full = (base + 8 <= (long long)E);
    if (full) {
        if (is64) {
            const long long* p = (const long long*)ei + (long long)E + base;
#pragma unroll
            for (int k = 0; k < 4; ++k) {
                longlong2 a = ((const longlong2*)p)[k];
                n_[2 * k] = (int)a.x;
                n_[2 * k + 1] = (int)a.y;
            }
        } else {
            const int* p = (const int*)ei + (long long)E + base;
            int4 a = ((const int4*)p)[0];
            int4 b = ((const int4*)p)[1];
            n_[0] = a.x; n_[1] = a.y; n_[2] = a.z; n_[3] = a.w;
            n_[4] = b.x; n_[5] = b.y; n_[6] = b.z; n_[7] = b.w;
        }
        float w[8];
#pragma unroll
        for (int k = 0; k < 8; ++k)
            w[k] = ((unsigned)n_[k] < (unsigned)N) ? wnode[n_[k]] : 1.0f;
        *(float4*)(wout + base) = make_float4(w[0], w[1], w[2], w[3]);
        *(float4*)(wout + base + 4) = make_float4(w[4], w[5], w[6], w[7]);
    } else {
#pragma unroll
        for (int k = 0; k < 8; ++k) {
            long long e = base + k;
            if (e < E) {
                int n = load_idx(ei, (long long)E + e, is64);
                wout[e] = ((unsigned)n < (unsigned)N) ? wnode[n] : 1.0f;
            }
        }
    }
}

// ---------------- fallback atomic path ----------------

__global__ void k_accum1(const void* __restrict__ ei, const float* __restrict__ src,
                         const float* __restrict__ tgt, float* __restrict__ cnt,
                         float* __restrict__ ssum, float* __restrict__ tsum,
                         const int* __restrict__ nz, int E, int N) {
    int e = blockIdx.x * blockDim.x + threadIdx.x;
    if (e >= E) return;
    int is64 = (*nz == 0);
    int d = load_idx(ei, e, is64);
    int n = load_idx(ei, (long long)E + e, is64);
    if ((unsigned)d >= (unsigned)N || (unsigned)n >= (unsigned)N) return;
    atomicAdd(&cnt[d], 1.0f);
    atomicAdd(&ssum[3 * d + 0], src[3 * n + 0]);
    atomicAdd(&ssum[3 * d + 1], src[3 * n + 1]);
    atomicAdd(&ssum[3 * d + 2], src[3 * n + 2]);
    atomicAdd(&tsum[3 * d + 0], tgt[3 * n + 0]);
    atomicAdd(&tsum[3 * d + 1], tgt[3 * n + 1]);
    atomicAdd(&tsum[3 * d + 2], tgt[3 * n + 2]);
}

__global__ void k_centers(float* __restrict__ cnt, float* __restrict__ ssum,
                          float* __restrict__ tsum, int N) {
    int i = blockIdx.x * blockDim.x + threadIdx.x;
    if (i >= N) return;
    float inv = 1.0f / fmaxf(cnt[i], 1.0f);
    ssum[3 * i + 0] *= inv; ssum[3 * i + 1] *= inv; ssum[3 * i + 2] *= inv;
    tsum[3 * i + 0] *= inv; tsum[3 * i + 1] *= inv; tsum[3 * i + 2] *= inv;
}

__global__ void k_accum2(const void* __restrict__ ei, const float* __restrict__ src,
                         const float* __restrict__ tgt, const float* __restrict__ ew,
                         const float* __restrict__ sc, const float* __restrict__ tc,
                         float* __restrict__ Mm, const int* __restrict__ nz, int E, int N) {
    int e = blockIdx.x * blockDim.x + threadIdx.x;
    if (e >= E) return;
    int is64 = (*nz == 0);
    int d = load_idx(ei, e, is64);
    int n = load_idx(ei, (long long)E + e, is64);
    if ((unsigned)d >= (unsigned)N || (unsigned)n >= (unsigned)N) return;
    float w = ew[e];
    float a0 = (src[3 * n + 0] - sc[3 * d + 0]) * w;
    float a1 = (src[3 * n + 1] - sc[3 * d + 1]) * w;
    float a2 = (src[3 * n + 2] - sc[3 * d + 2]) * w;
    float b0 = tgt[3 * n + 0] - tc[3 * d + 0];
    float b1 = tgt[3 * n + 1] - tc[3 * d + 1];
    float b2 = tgt[3 * n + 2] - tc[3 * d + 2];
    float* Md = Mm + 9 * (long long)d;
    atomicAdd(Md + 0, a0 * b0); atomicAdd(Md + 1, a0 * b1); atomicAdd(Md + 2, a0 * b2);
    atomicAdd(Md + 3, a1 * b0); atomicAdd(Md + 4, a1 * b1); atomicAdd(Md + 5, a1 * b2);
    atomicAdd(Md + 6, a2 * b0); atomicAdd(Md + 7, a2 * b1); atomicAdd(Md + 8, a2 * b2);
}

__global__ void k_kabsch(const float* __restrict__ Mm, const float* __restrict__ sc,
                         const float* __restrict__ tc, float* __restrict__ Rout,
                         float* __restrict__ Tout, int N) {
    int i = blockIdx.x * blockDim.x + threadIdx.x;
    if (i >= N) return;
    double M[3][3];
#pragma unroll
    for (int r = 0; r < 3; ++r)
#pragma unroll
        for (int c = 0; c < 3; ++c)
            M[r][c] = (double)Mm[9 * (long long)i + 3 * r + c];
    double Rm[3][3];
    kabsch_from_M(M, Rm);
    double s0 = sc[3 * i + 0], s1 = sc[3 * i + 1], s2 = sc[3 * i + 2];
    double t0 = tc[3 * i + 0], t1 = tc[3 * i + 1], t2 = tc[3 * i + 2];
#pragma unroll
    for (int r = 0; r < 3; ++r)
#pragma unroll
        for (int c = 0; c < 3; ++c)
            Rout[9 * (long long)i + 3 * r + c] = (float)Rm[r][c];
    Tout[3 * i + 0] = (float)(t0 - (Rm[0][0] * s0 + Rm[0][1] * s1 + Rm[0][2] * s2));
    Tout[3 * i + 1] = (float)(t1 - (Rm[1][0] * s0 + Rm[1][1] * s1 + Rm[1][2] * s2));
    Tout[3 * i + 2] = (float)(t2 - (Rm[2][0] * s0 + Rm[2][1] * s1 + Rm[2][2] * s2));
}

__global__ void k_weights_plain(const void* __restrict__ ei,
                                const float* __restrict__ src,
                                const float* __restrict__ tgt,
                                const float* __restrict__ R,
                                const float* __restrict__ T,
                                float* __restrict__ wout,
                                const int* __restrict__ nz, int E, int N) {
    int e = blockIdx.x * blockDim.x + threadIdx.x;
    if (e >= E) return;
    int is64 = (*nz == 0);
    int n = load_idx(ei, (long long)E + e, is64);
    float w = 1.0f;
    if ((unsigned)n < (unsigned)N) {
        float p0 = src[3 * n + 0], p1 = src[3 * n + 1], p2 = src[3 * n + 2];
        float q0 = tgt[3 * n + 0], q1 = tgt[3 * n + 1], q2 = tgt[3 * n + 2];
        const float* Rn = R + 9 * (long long)n;
        const float* Tn = T + 3 * (long long)n;
        float x0 = Rn[0] * p0 + Rn[1] * p1 + Rn[2] * p2 + Tn[0];
        float x1 = Rn[3] * p0 + Rn[4] * p1 + Rn[5] * p2 + Tn[1];
        float x2 = Rn[6] * p0 + Rn[7] * p1 + Rn[8] * p2 + Tn[2];
        float d0 = x0 - q0, d1 = x1 - q1, d2 = x2 - q2;
        float dd = d0 * d0 + d1 * d1 + d2 * d2;
        w = kSigma2 / (dd + kSigma2);
    }
    wout[e] = w;
}

extern "C" void kernel_launch(void* const* d_in, const int* in_sizes, int n_in,
                              void* d_out, int out_size, void* d_ws, size_t ws_size,
                              hipStream_t stream) {
    const float* src = (const float*)d_in[0];
    const float* tgt = (const float*)d_in[1];
    const void* ei = d_in[2];
    const float* ew = (const float*)d_in[3];
    int N = in_sizes[0] / 3;
    int E = in_sizes[3];

    float* out = (float*)d_out;
    float* Rout = out;
    float* Tout = out + (size_t)9 * N;
    float* Wout = out + (size_t)12 * N;

    int eb = (E + 255) / 256;
    int nb = (N + 255) / 256;
    int nbuckets = (N + 63) / 64;            // 64-node fine buckets
    int ncoarse = (nbuckets + 127) / 128;    // 8192-node coarse buckets
    int tiles = (int)(((long long)E + 2047) / 2048);
    int ntiles4 = (int)(((long long)E + 4095) / 4096);
    int wb8 = (int)(((long long)E + 2047) / 2048);

    // ws layout: [nz(16) | btot(2048) | cur16 | curC16(256) | boff |
    //             ccnt(ntiles4*16) | cbase(ntiles4*16) | thist(ntiles4*2048) | pad4 |
    //             sedge1 (E int2) | [sedge2 (E int2)] | pt(2(N+1) float4) | wnode(N) | momG(23N)]
    size_t ctrl_ints = 16 + 2048 + (size_t)nbuckets * 16 + 256
                     + (size_t)(nbuckets + 1) + (size_t)ntiles4 * 16 * 2
                     + (size_t)ntiles4 * 2048;
    ctrl_ints = (ctrl_ints + 3) & ~(size_t)3;
    size_t after1 = ctrl_ints + 2 * (size_t)E;
    after1 = (after1 + 3) & ~(size_t)3;
    size_t after2 = after1 + 2 * (size_t)E;
    after2 = (after2 + 3) & ~(size_t)3;
    size_t tail_ints = 8 * (size_t)(N + 1) + (size_t)N + 23 * (size_t)N;
    size_t needA = (after2 + tail_ints) * sizeof(int);
    size_t needB = (after1 + tail_ints) * sizeof(int);

    if (N <= 131072 && nbuckets <= 2048 && ws_size >= needB) {
        int twolevel = (ws_size >= needA) ? 1 : 0;
        int* nz = (int*)d_ws;
        int* btot = nz + 16;
        int* cur16 = btot + 2048;
        int* curC16 = cur16 + (size_t)nbuckets * 16;
        int* boff = curC16 + 256;
        int* ccnt = boff + (nbuckets + 1);
        int* cbase = ccnt + (size_t)ntiles4 * 16;
        int* thist = cbase + (size_t)ntiles4 * 16;
        int2* sedge1 = (int2*)((int*)d_ws + ctrl_ints);
        size_t tail_base = twolevel ? after2 : after1;
        int2* sedge2 = twolevel ? (int2*)((int*)d_ws + after1) : sedge1;
        float4* pt = (float4*)((int*)d_ws + tail_base);
        float* wnode = (float*)(pt + 2 * (size_t)(N + 1));
        float* momG = wnode + N;

        // only nz needs zeroing: thist/btot/ccnt/cbase/boff/cur16 are fully
        // (over)written each iteration by their producer kernels.
        hipMemsetAsync(d_ws, 0, 16 * sizeof(int), stream);

        k_pack<<<nb, 256, 0, stream>>>(src, tgt, pt, N, (const int*)ei, E, nz);
        k_bhist<<<ntiles4, 256, 0, stream>>>(ei, thist, ccnt, nz, E, N, nbuckets, ntiles4);
        k_bsum<<<128, 256, 0, stream>>>(thist, btot, ntiles4);
        k_scan<<<1, 1024, 0, stream>>>(btot, boff, cur16, ccnt, cbase,
                                       nbuckets, ntiles4, ncoarse);
        if (twolevel) {
            k_cscatter<<<ntiles4, 256, 0, stream>>>(ei, ew, cbase, sedge1, nz, E, N, ncoarse);
            k_fscatter<<<ntiles4, 256, 0, stream>>>(sedge1, cur16, boff, sedge2, E, nbuckets, ncoarse);
        } else {
            k_binscatter<<<tiles, 256, 0, stream>>>(ei, ew, cur16, sedge2, nz, E, N, nbuckets);
        }
        k_sortmoment<<<nbuckets, 256, 0, stream>>>(boff, sedge2, pt, momG, N);
        k_kabsch2<<<nb, 256, 0, stream>>>(momG, pt, Rout, Tout, wnode, N);
        k_wgather<<<wb8, 256, 0, stream>>>(ei, wnode, Wout, nz, E, N);
    } else {
        // fallback: atomic path
        float* cnt = (float*)d_ws;
        float* ssum = cnt + N;
        float* tsum = ssum + 3 * (size_t)N;
        float* Mm = tsum + 3 * (size_t)N;
        int* nz = (int*)(Mm + 9 * (size_t)N);
        size_t ws_bytes = (size_t)16 * N * sizeof(float) + 16;
        hipMemsetAsync(d_ws, 0, ws_bytes, stream);
        k_detect<<<1, 256, 0, stream>>>((const int*)ei, E, nz);
        k_accum1<<<eb, 256, 0, stream>>>(ei, src, tgt, cnt, ssum, tsum, nz, E, N);
        k_centers<<<nb, 256, 0, stream>>>(cnt, ssum, tsum, N);
        k_accum2<<<eb, 256, 0, stream>>>(ei, src, tgt, ew, ssum, tsum, Mm, nz, E, N);
        k_kabsch<<<nb, 256, 0, stream>>>(Mm, ssum, tsum, Rout, Tout, N);
        k_weights_plain<<<eb, 256, 0, stream>>>(ei, src, tgt, Rout, Tout, Wout, nz, E, N);
    }
}

// Round 8
// 226.152 us; speedup vs baseline: 1.0967x; 1.0967x over previous
//
#include <hip/hip_runtime.h>
#include <math.h>

static constexpr float kSigma2 = 0.05f * 0.05f;
static constexpr int kCap2 = 2560;  // max edges per 64-node bucket in fused LDS sort

__device__ __forceinline__ int load_idx(const void* ei, long long j, int is64) {
    if (is64) return (int)(((const long long*)ei)[j]);
    return ((const int*)ei)[j];
}

// Detect whether edge_index is int64 (all odd int32 words zero) or int32.
// (standalone version kept for the fallback path)
__global__ void k_detect(const int* __restrict__ ei32, int E, int* __restrict__ nz) {
    int t = threadIdx.x;
    int lim = E < 2048 ? E : 2048;
    int acc = 0;
    for (int k = t; k < lim; k += blockDim.x) acc |= ei32[2 * k + 1];
    if (acc) atomicOr(nz, 1);
}

// Pack points into one interleaved float4 array: pt[2n]=src_n, pt[2n+1]=tgt_n
// (both gathers for an edge hit ONE 64B line). Block 0 also runs the int64
// detection (fused to drop a whole-GPU-idle launch).
__global__ void k_pack(const float* __restrict__ src, const float* __restrict__ tgt,
                       float4* __restrict__ pt, int N,
                       const int* __restrict__ ei32, int E, int* __restrict__ nz) {
    int t = threadIdx.x;
    if (blockIdx.x == 0) {
        int lim = E < 2048 ? E : 2048;
        int acc = 0;
        for (int k = t; k < lim; k += 256) acc |= ei32[2 * k + 1];
        if (acc) atomicOr(nz, 1);
    }
    int i = blockIdx.x * blockDim.x + t;
    if (i >= N) return;
    pt[2 * i] = make_float4(src[3 * i + 0], src[3 * i + 1], src[3 * i + 2], 0.0f);
    pt[2 * i + 1] = make_float4(tgt[3 * i + 0], tgt[3 * i + 1], tgt[3 * i + 2], 0.0f);
}

// ---------------- shared Kabsch core (fp64, Jacobi on M^T M) ----------------
__device__ void kabsch_from_M(const double M[3][3], double Rm[3][3]) {
    Rm[0][0] = 1; Rm[0][1] = 0; Rm[0][2] = 0;
    Rm[1][0] = 0; Rm[1][1] = 1; Rm[1][2] = 0;
    Rm[2][0] = 0; Rm[2][1] = 0; Rm[2][2] = 1;

    double frob2 = 0.0;
#pragma unroll
    for (int r = 0; r < 3; ++r)
#pragma unroll
        for (int c = 0; c < 3; ++c) frob2 += M[r][c] * M[r][c];
    if (frob2 <= 1e-80) return;

    double A[3][3];
#pragma unroll
    for (int r = 0; r < 3; ++r)
#pragma unroll
        for (int c = 0; c < 3; ++c) {
            double s = 0.0;
#pragma unroll
            for (int k = 0; k < 3; ++k) s += M[k][r] * M[k][c];
            A[r][c] = s;
        }
    double V[3][3] = {{1, 0, 0}, {0, 1, 0}, {0, 0, 1}};
    const int PL[3] = {0, 0, 1};
    const int QL[3] = {1, 2, 2};
    // trace(A) == frob2; Jacobi converges quadratically, so a relative break
    // at 1e-14*frob2 stops after ~4-5 sweeps (was: always 15 full sweeps).
    double thr = 1e-14 * frob2;
    for (int sweep = 0; sweep < 15; ++sweep) {
        double off = fabs(A[0][1]) + fabs(A[0][2]) + fabs(A[1][2]);
        if (off <= thr) break;
        for (int pi = 0; pi < 3; ++pi) {
            int p = PL[pi], q = QL[pi], r3 = 3 - p - q;
            double apq = A[p][q];
            if (apq == 0.0) continue;
            double theta = (A[q][q] - A[p][p]) / (2.0 * apq);
            double t = copysign(1.0, theta) / (fabs(theta) + sqrt(theta * theta + 1.0));
            double c = 1.0 / sqrt(t * t + 1.0);
            double s = t * c;
            A[p][p] -= t * apq;
            A[q][q] += t * apq;
            A[p][q] = 0.0; A[q][p] = 0.0;
            double arp = A[r3][p], arq = A[r3][q];
            A[r3][p] = c * arp - s * arq; A[p][r3] = A[r3][p];
            A[r3][q] = s * arp + c * arq; A[q][r3] = A[r3][q];
#pragma unroll
            for (int k = 0; k < 3; ++k) {
                double vp = V[k][p], vq = V[k][q];
                V[k][p] = c * vp - s * vq;
                V[k][q] = s * vp + c * vq;
            }
        }
    }
    double lam[3] = {A[0][0], A[1][1], A[2][2]};
    int id0 = 0, id1 = 1, id2 = 2, tt;
    if (lam[id0] < lam[id1]) { tt = id0; id0 = id1; id1 = tt; }
    if (lam[id0] < lam[id2]) { tt = id0; id0 = id2; id2 = tt; }
    if (lam[id1] < lam[id2]) { tt = id1; id1 = id2; id2 = tt; }
    double v1[3] = {V[0][id0], V[1][id0], V[2][id0]};
    double v2[3] = {V[0][id1], V[1][id1], V[2][id1]};
    double v3[3] = {V[0][id2], V[1][id2], V[2][id2]};

    double b1[3], b2[3];
#pragma unroll
    for (int r = 0; r < 3; ++r) {
        b1[r] = M[r][0] * v1[0] + M[r][1] * v1[1] + M[r][2] * v1[2];
        b2[r] = M[r][0] * v2[0] + M[r][1] * v2[1] + M[r][2] * v2[2];
    }
    double n1 = sqrt(b1[0] * b1[0] + b1[1] * b1[1] + b1[2] * b1[2]);
    if (n1 <= 1e-150) return;
    double u1[3] = {b1[0] / n1, b1[1] / n1, b1[2] / n1};
    double dot = u1[0] * b2[0] + u1[1] * b2[1] + u1[2] * b2[2];
    double w2[3] = {b2[0] - dot * u1[0], b2[1] - dot * u1[1], b2[2] - dot * u1[2]};
    double n2 = sqrt(w2[0] * w2[0] + w2[1] * w2[1] + w2[2] * w2[2]);
    double u2[3];
    if (n2 > n1 * 1e-12) {
        u2[0] = w2[0] / n2; u2[1] = w2[1] / n2; u2[2] = w2[2] / n2;
    } else {
        double ex0 = (fabs(u1[0]) < 0.9) ? 1.0 : 0.0;
        double ex1 = 1.0 - ex0;
        double cx = u1[1] * 0.0 - u1[2] * ex1;
        double cy = u1[2] * ex0 - u1[0] * 0.0;
        double cz = u1[0] * ex1 - u1[1] * ex0;
        double cn = sqrt(cx * cx + cy * cy + cz * cz);
        u2[0] = cx / cn; u2[1] = cy / cn; u2[2] = cz / cn;
    }
    double u3[3] = {u1[1] * u2[2] - u1[2] * u2[1],
                    u1[2] * u2[0] - u1[0] * u2[2],
                    u1[0] * u2[1] - u1[1] * u2[0]};
    double dV = v1[0] * (v2[1] * v3[2] - v2[2] * v3[1])
              - v1[1] * (v2[0] * v3[2] - v2[2] * v3[0])
              + v1[2] * (v2[0] * v3[1] - v2[1] * v3[0]);
    dV = (dV >= 0.0) ? 1.0 : -1.0;
#pragma unroll
    for (int r = 0; r < 3; ++r)
#pragma unroll
        for (int c = 0; c < 3; ++c)
            Rm[r][c] = u1[r] * v1[c] + u2[r] * v2[c] + dV * u3[r] * v3[c];
}

// ---------------- bucketed counting-sort path ----------------
// fine bucket = dst >> 6 (64 nodes). final payload: x = (nbr<<6)|(dst&63), y = w bits.
// coarse bucket = dst >> 13 (128 fine buckets). intermediate payload:
//   x = (nbr<<13)|(dst&8191), y = w bits.
//
// Measured (r1/r2): global atomic RMWs cost per-TRANSACTION (~32B memory-side
// write each). The histogram and both scatters therefore use (near-)zero
// global atomics: per-tile histograms are written non-atomically and reduced
// by k_bsum; coarse scatter bases come from an exact prefix (ccnt->cbase).

// 4096 edges per block, 782 blocks. Non-atomic thist row; ccnt derived from
// the LDS histogram by 16-lane reduction (no per-edge ballots).
__global__ void __launch_bounds__(256) k_bhist(const void* __restrict__ ei,
                                               int* __restrict__ thist,
                                               int* __restrict__ ccnt,
                                               const int* __restrict__ nz,
                                               int E, int N, int nbuckets,
                                               int ntiles4) {
    __shared__ int lhist[2048];
    int t = threadIdx.x;
    long long tile = (long long)blockIdx.x * 4096;
    long long remll = (long long)E - tile;
    int rem = (remll < 4096) ? (int)remll : 4096;
    int is64 = (*nz == 0);
    for (int i = t; i < 2048; i += 256) lhist[i] = 0;
    __syncthreads();
    if (rem == 4096) {
        for (int it = 0; it < 2; ++it) {
            long long base = tile + (long long)it * 2048 + (long long)t * 8;
            int d[8];
            if (is64) {
                const long long* p = (const long long*)ei + base;
#pragma unroll
                for (int k = 0; k < 4; ++k) {
                    longlong2 v = ((const longlong2*)p)[k];
                    d[2 * k] = (int)v.x;
                    d[2 * k + 1] = (int)v.y;
                }
            } else {
                const int* p = (const int*)ei + base;
                int4 a = ((const int4*)p)[0];
                int4 bb = ((const int4*)p)[1];
                d[0] = a.x; d[1] = a.y; d[2] = a.z; d[3] = a.w;
                d[4] = bb.x; d[5] = bb.y; d[6] = bb.z; d[7] = bb.w;
            }
#pragma unroll
            for (int k = 0; k < 8; ++k)
                if ((unsigned)d[k] < (unsigned)N) atomicAdd(&lhist[d[k] >> 6], 1);
        }
    } else {
        for (int idx = t; idx < rem; idx += 256) {
            int dk = load_idx(ei, tile + idx, is64);
            if ((unsigned)dk < (unsigned)N) atomicAdd(&lhist[dk >> 6], 1);
        }
    }
    __syncthreads();
    // non-atomic per-tile histogram row: 8KB coalesced store.
    int* row = thist + (long long)blockIdx.x * 2048;
    for (int b = t; b < 2048; b += 256) row[b] = lhist[b];
    // per-tile coarse counts: thread t sums bins t*8..t*8+7, 16-lane reduce.
    int part = 0;
#pragma unroll
    for (int j = 0; j < 8; ++j) part += lhist[t * 8 + j];
#pragma unroll
    for (int off = 8; off >= 1; off >>= 1) part += __shfl_down(part, off, 16);
    if ((t & 15) == 0) ccnt[(long long)blockIdx.x * 16 + (t >> 4)] = part;
}

// Reduce thist over tiles -> btot[bin]. 128 blocks x 16 bins; L2-resident.
__global__ void __launch_bounds__(256) k_bsum(const int* __restrict__ thist,
                                              int* __restrict__ btot, int ntiles) {
    int t = threadIdx.x;
    int bin = blockIdx.x * 16 + (t >> 4);
    int j = t & 15;
    int s = 0;
    for (int i = j; i < ntiles; i += 16) s += thist[(long long)i * 2048 + bin];
#pragma unroll
    for (int off = 8; off >= 1; off >>= 1) s += __shfl_down(s, off, 16);
    if (j == 0) btot[bin] = s;
}

// fine exclusive scan (up to 2048 bins, 1024 thr x 2) -> boff, cur16.
// FUSED cscan phase: 16 waves then scan ccnt over tiles per coarse bin via
// 64-lane shuffle scans (no barriers in the chunk loop) -> cbase.
__global__ void k_scan(const int* __restrict__ btot, int* __restrict__ boff,
                       int* __restrict__ cur16,
                       const int* __restrict__ ccnt, int* __restrict__ cbase,
                       int nbuckets, int ntiles, int ncoarse) {
    __shared__ int sm[2048];
    __shared__ int exco[17];
    int t = threadIdx.x;
    int v0 = (t < nbuckets) ? btot[t] : 0;
    int v1 = (t + 1024 < nbuckets) ? btot[t + 1024] : 0;
    sm[t] = v0;
    sm[t + 1024] = v1;
    __syncthreads();
    for (int s = 1; s < 2048; s <<= 1) {
        int x0 = (t >= s) ? sm[t - s] : 0;
        int x1 = (t + 1024 >= s) ? sm[t + 1024 - s] : 0;
        __syncthreads();
        sm[t] += x0;
        sm[t + 1024] += x1;
        __syncthreads();
    }
    if (t < nbuckets) {
        int ex = sm[t] - v0;
        boff[t] = ex;
        cur16[t * 16] = ex;
        if ((t & 127) == 0) exco[t >> 7] = ex;
    }
    int t2 = t + 1024;
    if (t2 < nbuckets) {
        int ex = sm[t2] - v1;
        boff[t2] = ex;
        cur16[t2 * 16] = ex;
        if ((t2 & 127) == 0) exco[t2 >> 7] = ex;
    }
    if (t == nbuckets - 1) boff[nbuckets] = sm[t];
    if (t2 == nbuckets - 1) boff[nbuckets] = sm[t2];
    __syncthreads();
    // cscan phase: wave w scans coarse bin w over all tiles.
    int w = t >> 6, l = t & 63;
    if (w < ncoarse) {
        int run = exco[w];
        for (int start = 0; start < ntiles; start += 64) {
            int i = start + l;
            int v = (i < ntiles) ? ccnt[(long long)i * 16 + w] : 0;
            int x = v;
#pragma unroll
            for (int d = 1; d < 64; d <<= 1) {
                int y = __shfl_up(x, d, 64);
                if (l >= d) x += y;
            }
            if (i < ntiles) cbase[(long long)i * 16 + w] = run + x - v;
            run += __shfl(x, 63, 64);
        }
    }
}

// Level-1 scatter: raw edges -> coarse-sorted sedge1 (<=16 bins, long runs).
// 4096-edge tiles; wave-ballot ranking; ZERO global atomics (bases come from
// the precomputed cbase prefix).
__global__ void __launch_bounds__(256) k_cscatter(const void* __restrict__ ei,
                                                  const float* __restrict__ ew,
                                                  const int* __restrict__ cbase,
                                                  int2* __restrict__ sedge1,
                                                  const int* __restrict__ nz,
                                                  int E, int N, int ncoarse) {
    __shared__ int2 stage[4096];
    __shared__ unsigned char binOf[4096];
    __shared__ int hist[16];
    __shared__ int excl[16];
    __shared__ int gbase[16];
    __shared__ int woffs[4][16];   // per-wave running bin counts
    __shared__ int wbase[4][16];   // per-wave base within bin (tile-local)
    int t = threadIdx.x;
    int w = t >> 6, lane = t & 63;
    unsigned long long lanebelow = ((unsigned long long)1 << lane) - 1;
    long long tile = (long long)blockIdx.x * 4096;
    long long remll = (long long)E - tile;
    int rem = (remll < 4096) ? (int)remll : 4096;
    int is64 = (*nz == 0);
    if (t < 16) hist[t] = 0;
    if (t < 64) ((int*)woffs)[t] = 0;
    __syncthreads();

    int mybin[16];
    int mypos[16];   // position within this wave's portion of the bin
    int2 mypay[16];
#pragma unroll
    for (int h = 0; h < 2; ++h) {
        int dd[8], nn[8];
        float ww[8];
        int cnt8 = 0;
        int coff = h * 2048 + t * 8;
        long long cb = tile + coff;
        if (coff + 8 <= rem) {
            if (is64) {
                const long long* pd = (const long long*)ei + cb;
                const long long* pn = (const long long*)ei + (long long)E + cb;
#pragma unroll
                for (int k = 0; k < 4; ++k) {
                    longlong2 vd = ((const longlong2*)pd)[k];
                    longlong2 vn = ((const longlong2*)pn)[k];
                    dd[2 * k] = (int)vd.x; dd[2 * k + 1] = (int)vd.y;
                    nn[2 * k] = (int)vn.x; nn[2 * k + 1] = (int)vn.y;
                }
            } else {
                const int* pd = (const int*)ei + cb;
                const int* pn = (const int*)ei + (long long)E + cb;
                int4 a = ((const int4*)pd)[0], b = ((const int4*)pd)[1];
                int4 c = ((const int4*)pn)[0], d = ((const int4*)pn)[1];
                dd[0] = a.x; dd[1] = a.y; dd[2] = a.z; dd[3] = a.w;
                dd[4] = b.x; dd[5] = b.y; dd[6] = b.z; dd[7] = b.w;
                nn[0] = c.x; nn[1] = c.y; nn[2] = c.z; nn[3] = c.w;
                nn[4] = d.x; nn[5] = d.y; nn[6] = d.z; nn[7] = d.w;
            }
            const float* pw = ew + cb;
            float4 wa = ((const float4*)pw)[0], wb = ((const float4*)pw)[1];
            ww[0] = wa.x; ww[1] = wa.y; ww[2] = wa.z; ww[3] = wa.w;
            ww[4] = wb.x; ww[5] = wb.y; ww[6] = wb.z; ww[7] = wb.w;
            cnt8 = 8;
        } else {
#pragma unroll
            for (int k = 0; k < 8; ++k) {
                if (coff + k < rem) {
                    dd[cnt8] = load_idx(ei, cb + k, is64);
                    nn[cnt8] = load_idx(ei, (long long)E + cb + k, is64);
                    ww[cnt8] = ew[cb + k];
                    ++cnt8;
                }
            }
        }
        // ballot-ranked binning: per round, each lane handles one edge
#pragma unroll
        for (int k = 0; k < 8; ++k) {
            int r = h * 8 + k;
            int bin = -1;
            if (k < cnt8) {
                int d = dd[k];
                if ((unsigned)d < (unsigned)N) {
                    int n = nn[k];
                    if ((unsigned)n >= (unsigned)N) n = N;  // sentinel; filtered later
                    bin = d >> 13;
                    mypay[r].x = (n << 13) | (d & 8191);
                    mypay[r].y = __float_as_int(ww[k]);
                }
            }
            mybin[r] = bin;
            unsigned long long valid = __ballot(bin >= 0);
            unsigned long long v0 = __ballot(bin & 1);
            unsigned long long v1 = __ballot(bin & 2);
            unsigned long long v2 = __ballot(bin & 4);
            unsigned long long v3 = __ballot(bin & 8);
            if (bin >= 0) {
                unsigned long long m = valid;
                m &= (bin & 1) ? v0 : ~v0;
                m &= (bin & 2) ? v1 : ~v1;
                m &= (bin & 4) ? v2 : ~v2;
                m &= (bin & 8) ? v3 : ~v3;
                int rank = __popcll(m & lanebelow);
                int cnt = __popcll(m);
                int cur = woffs[w][bin];
                mypos[r] = cur + rank;
                if (rank == 0) woffs[w][bin] = cur + cnt;
            }
        }
    }
    __syncthreads();
    // cross-wave bases: 64 LDS atomics
    if (t < 64) {
        int w2 = t >> 4, b = t & 15;
        int c = woffs[w2][b];
        wbase[w2][b] = (c > 0) ? atomicAdd(&hist[b], c) : 0;
    }
    __syncthreads();
    if (t == 0) {
        int run = 0;
#pragma unroll
        for (int c = 0; c < 16; ++c) { excl[c] = run; run += hist[c]; }
    }
    __syncthreads();
#pragma unroll
    for (int r = 0; r < 16; ++r) {
        if (mybin[r] >= 0) {
            int lpos = excl[mybin[r]] + wbase[w][mybin[r]] + mypos[r];
            stage[lpos] = mypay[r];
            binOf[lpos] = (unsigned char)mybin[r];
        }
    }
    if (t < 16) gbase[t] = cbase[(long long)blockIdx.x * 16 + t];
    __syncthreads();
    int total = excl[15] + hist[15];
    for (int lpos = t; lpos < total; lpos += 256) {
        int c = binOf[lpos];
        sedge1[(long long)gbase[c] + (lpos - excl[c])] = stage[lpos];
    }
}

// Level-2 scatter: coarse-sorted sedge1 -> fine-sorted sedge2 (repacks payload).
// 4096-edge tiles, wave-ballot ranking over a <=256-bin window (tile spans at
// most 2 coarse bins with uniform data; wider spans take the rare slow path).
// Per-bin runs are ~32 edges = 256B coalesced writes.
__global__ void __launch_bounds__(256) k_fscatter(const int2* __restrict__ sedge1,
                                                  int* __restrict__ cur16,
                                                  const int* __restrict__ boff,
                                                  int2* __restrict__ sedge2,
                                                  int E, int nbuckets, int ncoarse) {
    __shared__ int2 stage[4096];
    __shared__ unsigned short binOf[4096];
    __shared__ int hist[256];
    __shared__ int lincl[256];
    __shared__ int gbase[256];
    __shared__ int woffs[4][256];   // per-wave running bin counts
    __shared__ int wbase[4][256];   // per-wave base within bin (tile-local)
    __shared__ int co[17];
    __shared__ int s_clo, s_W;
    int t = threadIdx.x;
    int w = t >> 6, lane = t & 63;
    unsigned long long lanebelow = ((unsigned long long)1 << lane) - 1;
    if (t <= ncoarse) {
        int f = t * 128;
        if (f > nbuckets) f = nbuckets;
        co[t] = boff[f];
    }
    __syncthreads();
    int Ev = co[ncoarse];
    long long tile = (long long)blockIdx.x * 4096;
    if (tile >= Ev) return;
    long long remll = (long long)Ev - tile;
    int rem = (remll < 4096) ? (int)remll : 4096;

    if (t == 0) {
        long long p0 = tile, p1 = tile + rem - 1;
        int c0 = 0;
        while (c0 + 1 < ncoarse && p0 >= co[c0 + 1]) ++c0;
        int c1 = c0;
        while (c1 + 1 < ncoarse && p1 >= co[c1 + 1]) ++c1;
        s_clo = c0;
        s_W = (c1 - c0 + 1) * 128;
    }
    hist[t] = 0;
    for (int i = t; i < 1024; i += 256) ((int*)woffs)[i] = 0;
    __syncthreads();
    int clo = s_clo, W = s_W;

    // load 16 edges/thread (two 2048-edge halves, int4 vector loads)
    int2 pay[16];
#pragma unroll
    for (int h = 0; h < 2; ++h) {
        int coff = h * 2048 + t * 8;
        if (coff + 8 <= rem) {
            const int4* p4 = (const int4*)(sedge1 + tile + coff);
#pragma unroll
            for (int k = 0; k < 4; ++k) {
                int4 v = p4[k];
                pay[h * 8 + 2 * k].x = v.x;     pay[h * 8 + 2 * k].y = v.y;
                pay[h * 8 + 2 * k + 1].x = v.z; pay[h * 8 + 2 * k + 1].y = v.w;
            }
        } else {
#pragma unroll
            for (int k = 0; k < 8; ++k)
                if (coff + k < rem) pay[h * 8 + k] = sedge1[tile + coff + k];
        }
    }

    if (W > 256) {
        // slow path (only if a tile spans >=3 coarse bins -- requires a tiny
        // coarse bin; essentially never with uniform data)
#pragma unroll
        for (int h = 0; h < 2; ++h) {
#pragma unroll
            for (int k = 0; k < 8; ++k) {
                int coff = h * 2048 + t * 8 + k;
                if (coff < rem) {
                    long long pos = tile + coff;
                    int x1 = pay[h * 8 + k].x;
                    int c = clo;
                    while (c + 1 < ncoarse && pos >= co[c + 1]) ++c;
                    unsigned nbr = ((unsigned)x1) >> 13;
                    int fin = c * 128 + ((x1 & 8191) >> 6);
                    int gpos = atomicAdd(&cur16[fin * 16], 1);
                    int2 out;
                    out.x = (int)((nbr << 6) | (unsigned)(x1 & 63));
                    out.y = pay[h * 8 + k].y;
                    sedge2[gpos] = out;
                }
            }
        }
        return;
    }

    // ballot-ranked binning (8-bit rel): no per-edge LDS atomics
    int mybin[16];
    int mypos[16];
#pragma unroll
    for (int h = 0; h < 2; ++h) {
#pragma unroll
        for (int k = 0; k < 8; ++k) {
            int r = h * 8 + k;
            int coff = h * 2048 + t * 8 + k;
            int bin = -1;
            if (coff < rem) {
                long long pos = tile + coff;
                int x1 = pay[r].x;
                int c = clo;
                while (c + 1 < ncoarse && pos >= co[c + 1]) ++c;
                bin = (c - clo) * 128 + ((x1 & 8191) >> 6);
            }
            mybin[r] = bin;
            unsigned long long vm = __ballot(bin >= 0);
            unsigned long long b0 = __ballot(bin & 1);
            unsigned long long b1 = __ballot(bin & 2);
            unsigned long long b2 = __ballot(bin & 4);
            unsigned long long b3 = __ballot(bin & 8);
            unsigned long long b4 = __ballot(bin & 16);
            unsigned long long b5 = __ballot(bin & 32);
            unsigned long long b6 = __ballot(bin & 64);
            unsigned long long b7 = __ballot(bin & 128);
            if (bin >= 0) {
                unsigned long long m = vm;
                m &= (bin & 1) ? b0 : ~b0;
                m &= (bin & 2) ? b1 : ~b1;
                m &= (bin & 4) ? b2 : ~b2;
                m &= (bin & 8) ? b3 : ~b3;
                m &= (bin & 16) ? b4 : ~b4;
                m &= (bin & 32) ? b5 : ~b5;
                m &= (bin & 64) ? b6 : ~b6;
                m &= (bin & 128) ? b7 : ~b7;
                int rank = __popcll(m & lanebelow);
                int cnt = __popcll(m);
                int cur = woffs[w][bin];
                mypos[r] = cur + rank;
                if (rank == 0) woffs[w][bin] = cur + cnt;
            }
        }
    }
    __syncthreads();
    // cross-wave bases: thread t handles bin t across the 4 waves
    {
        int c0 = woffs[0][t], c1 = woffs[1][t], c2 = woffs[2][t], c3 = woffs[3][t];
        int run = 0;
        wbase[0][t] = run; run += c0;
        wbase[1][t] = run; run += c1;
        wbase[2][t] = run; run += c2;
        wbase[3][t] = run; run += c3;
        hist[t] = run;
    }
    __syncthreads();
    lincl[t] = hist[t];
    __syncthreads();
    for (int s = 1; s < 256; s <<= 1) {
        int x = (t >= s) ? lincl[t - s] : 0;
        __syncthreads();
        lincl[t] += x;
        __syncthreads();
    }
#pragma unroll
    for (int r = 0; r < 16; ++r) {
        if (mybin[r] >= 0) {
            int bin = mybin[r];
            int ex = lincl[bin] - hist[bin];
            int lpos = ex + wbase[w][bin] + mypos[r];
            int x1 = pay[r].x;
            unsigned nbr = ((unsigned)x1) >> 13;
            int2 out;
            out.x = (int)((nbr << 6) | (unsigned)(x1 & 63));
            out.y = pay[r].y;
            stage[lpos] = out;
            binOf[lpos] = (unsigned short)bin;
        }
    }
    {
        int c = hist[t];
        int fin = clo * 128 + t;
        gbase[t] = (c > 0 && fin < nbuckets) ? atomicAdd(&cur16[fin * 16], c) : 0;
    }
    __syncthreads();
    int total = lincl[255];
    for (int lpos = t; lpos < total; lpos += 256) {
        int rel = binOf[lpos];
        int ex = lincl[rel] - hist[rel];
        sedge2[gbase[rel] + (lpos - ex)] = stage[lpos];
    }
}

// Single-level scatter (fallback when ws can't hold two edge buffers).
__global__ void __launch_bounds__(256) k_binscatter(const void* __restrict__ ei,
                                                    const float* __restrict__ ew,
                                                    int* __restrict__ cur16,
                                                    int2* __restrict__ sedge,
                                                    const int* __restrict__ nz,
                                                    int E, int N, int nbuckets) {
    __shared__ int2 stage[2048];
    __shared__ unsigned short binOf[2048];
    __shared__ int lhist[2048];
    __shared__ int lincl[2048];
    __shared__ int gbase[2048];
    int t = threadIdx.x;
    long long tile = (long long)blockIdx.x * 2048;
    long long remll = (long long)E - tile;
    int rem = (remll < 2048) ? (int)remll : 2048;
    int is64 = (*nz == 0);
    for (int i = t; i < 2048; i += 256) lhist[i] = 0;
    __syncthreads();

    int dd[8], nn[8];
    float ww[8];
    int cnt8 = 0;
    if (rem == 2048) {
        if (is64) {
            const long long* pd = (const long long*)ei + tile + (long long)t * 8;
            const long long* pn = (const long long*)ei + (long long)E + tile + (long long)t * 8;
#pragma unroll
            for (int k = 0; k < 4; ++k) {
                longlong2 vd = ((const longlong2*)pd)[k];
                longlong2 vn = ((const longlong2*)pn)[k];
                dd[2 * k] = (int)vd.x; dd[2 * k + 1] = (int)vd.y;
                nn[2 * k] = (int)vn.x; nn[2 * k + 1] = (int)vn.y;
            }
        } else {
            const int* pd = (const int*)ei + tile + (long long)t * 8;
            const int* pn = (const int*)ei + (long long)E + tile + (long long)t * 8;
            int4 a = ((const int4*)pd)[0], b = ((const int4*)pd)[1];
            int4 c = ((const int4*)pn)[0], d = ((const int4*)pn)[1];
            dd[0] = a.x; dd[1] = a.y; dd[2] = a.z; dd[3] = a.w;
            dd[4] = b.x; dd[5] = b.y; dd[6] = b.z; dd[7] = b.w;
            nn[0] = c.x; nn[1] = c.y; nn[2] = c.z; nn[3] = c.w;
            nn[4] = d.x; nn[5] = d.y; nn[6] = d.z; nn[7] = d.w;
        }
        const float* pw = ew + tile + (long long)t * 8;
        float4 wa = ((const float4*)pw)[0], wb = ((const float4*)pw)[1];
        ww[0] = wa.x; ww[1] = wa.y; ww[2] = wa.z; ww[3] = wa.w;
        ww[4] = wb.x; ww[5] = wb.y; ww[6] = wb.z; ww[7] = wb.w;
        cnt8 = 8;
    } else {
        int base = t * 8;
#pragma unroll
        for (int k = 0; k < 8; ++k) {
            int idx = base + k;
            if (idx < rem) {
                long long e = tile + idx;
                dd[cnt8] = load_idx(ei, e, is64);
                nn[cnt8] = load_idx(ei, (long long)E + e, is64);
                ww[cnt8] = ew[e];
                ++cnt8;
            }
        }
    }

    int mybin[8];
    int myrank[8];
    int2 mypay[8];
#pragma unroll
    for (int k = 0; k < 8; ++k) {
        mybin[k] = -1;
        if (k < cnt8) {
            int d = dd[k];
            if ((unsigned)d < (unsigned)N) {
                int n = nn[k];
                if ((unsigned)n >= (unsigned)N) n = N;  // sentinel
                int bb = d >> 6;
                mybin[k] = bb;
                myrank[k] = atomicAdd(&lhist[bb], 1);
                mypay[k].x = (n << 6) | (d & 63);
                mypay[k].y = __float_as_int(ww[k]);
            }
        }
    }
    __syncthreads();
    for (int i = t; i < 2048; i += 256) lincl[i] = lhist[i];
    __syncthreads();
    for (int s = 1; s < 2048; s <<= 1) {
        int tmp[8];
#pragma unroll
        for (int j = 0; j < 8; ++j) {
            int i = (j << 8) + t;
            tmp[j] = (i >= s) ? lincl[i - s] : 0;
        }
        __syncthreads();
#pragma unroll
        for (int j = 0; j < 8; ++j) {
            int i = (j << 8) + t;
            lincl[i] += tmp[j];
        }
        __syncthreads();
    }
#pragma unroll
    for (int k = 0; k < 8; ++k) {
        if (mybin[k] >= 0) {
            int ex = lincl[mybin[k]] - lhist[mybin[k]];
            int lpos = ex + myrank[k];
            stage[lpos] = mypay[k];
            binOf[lpos] = (unsigned short)mybin[k];
        }
    }
    __syncthreads();
    for (int bb = t; bb < 2048; bb += 256) {
        int c = lhist[bb];
        gbase[bb] = (c > 0 && bb < nbuckets) ? atomicAdd(&cur16[bb * 16], c) : 0;
    }
    __syncthreads();
    int total = lincl[2047];
    for (int lpos = t; lpos < total; lpos += 256) {
        int bb = binOf[lpos];
        int ex = lincl[bb] - lhist[bb];
        sedge[gbase[bb] + (lpos - ex)] = stage[lpos];
    }
}

// 23-moment accumulate for one edge.
__device__ __forceinline__ void mom_acc(float v[23], float w_, float4 a, float4 bb) {
    float sx = a.x, sy = a.y, sz = a.z;
    float tx = bb.x, ty = bb.y, tz = bb.z;
    v[0] += 1.0f;
    v[1] += sx; v[2] += sy; v[3] += sz;
    v[4] += tx; v[5] += ty; v[6] += tz;
    v[7] += w_;
    float wsx = w_ * sx, wsy = w_ * sy, wsz = w_ * sz;
    v[8] += wsx; v[9] += wsy; v[10] += wsz;
    v[11] += w_ * tx; v[12] += w_ * ty; v[13] += w_ * tz;
    v[14] += wsx * tx; v[15] += wsx * ty; v[16] += wsx * tz;
    v[17] += wsy * tx; v[18] += wsy * ty; v[19] += wsy * tz;
    v[20] += wsz * tx; v[21] += wsz * ty; v[22] += wsz * tz;
}

// Fused per-bucket sort (64 nodes, in LDS, no write-back) + 23-moment pass.
// Ballot-ranked counting sort, zero per-edge atomics. Sort loads are grouped
// in chunks of 5 (fully unrolled, compile-time indices, NO break -- r7's
// break pattern sent pay[] to scratch, +26MB spill traffic) for 5-deep MLP.
// Moment pass: interleaved pt[] (1 line/edge) + 4x unrolled gather walk.
__global__ void __launch_bounds__(256) k_sortmoment(const int* __restrict__ boff,
                                                    const int2* __restrict__ sedge2,
                                                    const float4* __restrict__ pt,
                                                    float* __restrict__ momG, int N) {
    __shared__ int2 sorted[kCap2];
    __shared__ int hist[64];
    __shared__ int offs[64];
    __shared__ int scanbuf[64];
    __shared__ int woffs[4][64];   // per-wave per-bin counts
    __shared__ int wbase[4][64];   // per-wave exclusive base within bin
    int b = blockIdx.x, t = threadIdx.x;
    int w = t >> 6, lane = t & 63;
    unsigned long long lanebelow = ((unsigned long long)1 << lane) - 1;
    int e0 = boff[b], e1 = boff[b + 1];
    int cnt = e1 - e0;
    int inlds = (cnt <= kCap2);
    if (t < 64) hist[t] = 0;
    ((int*)woffs)[t] = 0;   // 256 threads cover all 4x64 entries
    __syncthreads();
    if (inlds) {
        int2 pay[10];
        int mypos[10];
#pragma unroll
        for (int ch = 0; ch < 2; ++ch) {
            // phase A: 5 guarded loads, all independent -> in flight together
#pragma unroll
            for (int k = 0; k < 5; ++k) {
                int r = ch * 5 + k;
                int idx = r * 256 + t;
                if (idx < cnt) pay[r] = sedge2[e0 + idx];
            }
            // phase B: 5 ballot-ranking rounds (register-only)
#pragma unroll
            for (int k = 0; k < 5; ++k) {
                int r = ch * 5 + k;
                int idx = r * 256 + t;
                int bin = (idx < cnt) ? (pay[r].x & 63) : -1;
                unsigned long long vm = __ballot(bin >= 0);
                unsigned long long b0 = __ballot(bin & 1);
                unsigned long long b1 = __ballot(bin & 2);
                unsigned long long b2 = __ballot(bin & 4);
                unsigned long long b3 = __ballot(bin & 8);
                unsigned long long b4 = __ballot(bin & 16);
                unsigned long long b5 = __ballot(bin & 32);
                if (bin >= 0) {
                    unsigned long long m = vm;
                    m &= (bin & 1) ? b0 : ~b0;
                    m &= (bin & 2) ? b1 : ~b1;
                    m &= (bin & 4) ? b2 : ~b2;
                    m &= (bin & 8) ? b3 : ~b3;
                    m &= (bin & 16) ? b4 : ~b4;
                    m &= (bin & 32) ? b5 : ~b5;
                    int rank = __popcll(m & lanebelow);
                    int cm = __popcll(m);
                    int curv = woffs[w][bin];
                    mypos[r] = curv + rank;
                    if (rank == 0) woffs[w][bin] = curv + cm;
                }
            }
        }
        __syncthreads();
        {   // cross-wave exclusive bases: 256 atomics, <=4 contenders/address
            int w2 = t >> 6, bb = t & 63;
            int c = woffs[w2][bb];
            wbase[w2][bb] = (c > 0) ? atomicAdd(&hist[bb], c) : 0;
        }
        __syncthreads();
        if (t < 64) scanbuf[t] = hist[t];
        __syncthreads();
        for (int s = 1; s < 64; s <<= 1) {
            int v = 0;
            if (t < 64 && t >= s) v = scanbuf[t - s];
            __syncthreads();
            if (t < 64) scanbuf[t] += v;
            __syncthreads();
        }
        if (t < 64) offs[t] = scanbuf[t] - hist[t];
        __syncthreads();
#pragma unroll
        for (int r = 0; r < 10; ++r) {
            int idx = r * 256 + t;
            if (idx < cnt) {
                int bin = pay[r].x & 63;
                sorted[offs[bin] + wbase[w][bin] + mypos[r]] = pay[r];
            }
        }
        __syncthreads();
    }
    int oct = t >> 3, lane8 = t & 7;
#pragma unroll
    for (int rr = 0; rr < 2; ++rr) {
        int nl = oct + rr * 32;
        long long node = (long long)b * 64 + nl;
        float v[23];
#pragma unroll
        for (int i = 0; i < 23; ++i) v[i] = 0.0f;
        if (node < N) {
            if (inlds) {
                int start = offs[nl];
                int cn = hist[nl];
                int j = lane8;
                // 4x unroll: issue all four edges' gathers before accumulating
                // (sentinel n==N reads the valid dummy slot pt[2N..2N+1]).
                for (; j + 24 < cn; j += 32) {
                    int2 p0 = sorted[start + j];
                    int2 p1 = sorted[start + j + 8];
                    int2 p2 = sorted[start + j + 16];
                    int2 p3 = sorted[start + j + 24];
                    unsigned n0 = ((unsigned)p0.x) >> 6;
                    unsigned n1 = ((unsigned)p1.x) >> 6;
                    unsigned n2 = ((unsigned)p2.x) >> 6;
                    unsigned n3 = ((unsigned)p3.x) >> 6;
                    float4 a0 = pt[2 * n0], b0v = pt[2 * n0 + 1];
                    float4 a1 = pt[2 * n1], b1v = pt[2 * n1 + 1];
                    float4 a2 = pt[2 * n2], b2v = pt[2 * n2 + 1];
                    float4 a3 = pt[2 * n3], b3v = pt[2 * n3 + 1];
                    if (n0 < (unsigned)N) mom_acc(v, __int_as_float(p0.y), a0, b0v);
                    if (n1 < (unsigned)N) mom_acc(v, __int_as_float(p1.y), a1, b1v);
                    if (n2 < (unsigned)N) mom_acc(v, __int_as_float(p2.y), a2, b2v);
                    if (n3 < (unsigned)N) mom_acc(v, __int_as_float(p3.y), a3, b3v);
                }
                for (; j + 8 < cn; j += 16) {
                    int2 p0 = sorted[start + j];
                    int2 p1 = sorted[start + j + 8];
                    unsigned n0 = ((unsigned)p0.x) >> 6;
                    unsigned n1 = ((unsigned)p1.x) >> 6;
                    float4 a0 = pt[2 * n0], b0v = pt[2 * n0 + 1];
                    float4 a1 = pt[2 * n1], b1v = pt[2 * n1 + 1];
                    if (n0 < (unsigned)N) mom_acc(v, __int_as_float(p0.y), a0, b0v);
                    if (n1 < (unsigned)N) mom_acc(v, __int_as_float(p1.y), a1, b1v);
                }
                if (j < cn) {
                    int2 p = sorted[start + j];
                    unsigned n = ((unsigned)p.x) >> 6;
                    float4 a = pt[2 * n], bb = pt[2 * n + 1];
                    if (n < (unsigned)N) mom_acc(v, __int_as_float(p.y), a, bb);
                }
            } else {
                for (int j = lane8; j < cnt; j += 8) {
                    int2 p = sedge2[e0 + j];
                    if ((p.x & 63) != nl) continue;
                    unsigned n = ((unsigned)p.x) >> 6;
                    if (n >= (unsigned)N) continue;
                    float4 a = pt[2 * n], bb = pt[2 * n + 1];
                    mom_acc(v, __int_as_float(p.y), a, bb);
                }
            }
        }
#pragma unroll
        for (int m = 1; m < 8; m <<= 1) {
#pragma unroll
            for (int i = 0; i < 23; ++i) v[i] += __shfl_xor(v[i], m, 64);
        }
        if (lane8 == 0 && node < N) {
#pragma unroll
            for (int i = 0; i < 23; ++i) momG[(size_t)i * N + node] = v[i];
        }
    }
}

// One thread per node: expand moments -> M, fp64 Kabsch, R/T/wnode.
__global__ void __launch_bounds__(256) k_kabsch2(const float* __restrict__ momG,
                                                 const float4* __restrict__ pt,
                                                 float* __restrict__ Rout,
                                                 float* __restrict__ Tout,
                                                 float* __restrict__ wnode, int N) {
    int i = blockIdx.x * blockDim.x + threadIdx.x;
    if (i >= N) return;
    float m[23];
#pragma unroll
    for (int k = 0; k < 23; ++k) m[k] = momG[(size_t)k * N + i];
    double cntv = (double)m[0];
    double inv = 1.0 / fmax(cntv, 1.0);
    double sb[3] = {m[1] * inv, m[2] * inv, m[3] * inv};
    double tb[3] = {m[4] * inv, m[5] * inv, m[6] * inv};
    double Sw = m[7];
    double Sws[3] = {m[8], m[9], m[10]};
    double Swt[3] = {m[11], m[12], m[13]};
    double M[3][3];
#pragma unroll
    for (int r = 0; r < 3; ++r)
#pragma unroll
        for (int c = 0; c < 3; ++c)
            M[r][c] = (double)m[14 + 3 * r + c]
                    - sb[r] * Swt[c] - Sws[r] * tb[c] + Sw * sb[r] * tb[c];
    double Rm[3][3];
    kabsch_from_M(M, Rm);
    double T0 = tb[0] - (Rm[0][0] * sb[0] + Rm[0][1] * sb[1] + Rm[0][2] * sb[2]);
    double T1 = tb[1] - (Rm[1][0] * sb[0] + Rm[1][1] * sb[1] + Rm[1][2] * sb[2]);
    double T2 = tb[2] - (Rm[2][0] * sb[0] + Rm[2][1] * sb[1] + Rm[2][2] * sb[2]);
#pragma unroll
    for (int r = 0; r < 3; ++r)
#pragma unroll
        for (int c = 0; c < 3; ++c)
            Rout[9 * (long long)i + 3 * r + c] = (float)Rm[r][c];
    Tout[3 * i + 0] = (float)T0;
    Tout[3 * i + 1] = (float)T1;
    Tout[3 * i + 2] = (float)T2;
    float4 a = pt[2 * i];
    float4 q = pt[2 * i + 1];
    double x0 = Rm[0][0] * a.x + Rm[0][1] * a.y + Rm[0][2] * a.z + T0;
    double x1 = Rm[1][0] * a.x + Rm[1][1] * a.y + Rm[1][2] * a.z + T1;
    double x2 = Rm[2][0] * a.x + Rm[2][1] * a.y + Rm[2][2] * a.z + T2;
    double d0 = x0 - q.x, d1 = x1 - q.y, d2 = x2 - q.z;
    double dd = d0 * d0 + d1 * d1 + d2 * d2;
    wnode[i] = (float)((double)kSigma2 / (dd + (double)kSigma2));
}

// wout[e] = wnode[nbr[e]] (8 edges/thread, vector loads, float4 stores).
__global__ void __launch_bounds__(256) k_wgather(const void* __restrict__ ei,
                                                 const float* __restrict__ wnode,
                                                 float* __restrict__ wout,
                                                 const int* __restrict__ nz,
                                                 int E, int N) {
    int gid = blockIdx.x * blockDim.x + threadIdx.x;
    long long base = (long long)gid * 8;
    if (base >= E) return;
    int is64 = (*nz == 0);
    int n_[8];
    int full = (base + 8 <= (long long)E);
    if (full) {
        if (is64) {
            const long long* p = (const long long*)ei + (long long)E + base;
#pragma unroll
            for (int k = 0; k < 4; ++k) {
                longlong2 a = ((const longlong2*)p)[k];
                n_[2 * k] = (int)a.x;
                n_[2 * k + 1] = (int)a.y;
            }
        } else {
            const int* p = (const int*)ei + (long long)E + base;
            int4 a = ((const int4*)p)[0];
            int4 b = ((const int4*)p)[1];
            n_[0] = a.x; n_[1] = a.y; n_[2] = a.z; n_[3] = a.w;
            n_[4] = b.x; n_[5] = b.y; n_[6] = b.z; n_[7] = b.w;
        }
        float w[8];
#pragma unroll
        for (int k = 0; k < 8; ++k)
            w[k] = ((unsigned)n_[k] < (unsigned)N) ? wnode[n_[k]] : 1.0f;
        *(float4*)(wout + base) = make_float4(w[0], w[1], w[2], w[3]);
        *(float4*)(wout + base + 4) = make_float4(w[4], w[5], w[6], w[7]);
    } else {
#pragma unroll
        for (int k = 0; k < 8; ++k) {
            long long e = base + k;
            if (e < E) {
                int n = load_idx(ei, (long long)E + e, is64);
                wout[e] = ((unsigned)n < (unsigned)N) ? wnode[n] : 1.0f;
            }
        }
    }
}

// ---------------- fallback atomic path ----------------

__global__ void k_accum1(const void* __restrict__ ei, const float* __restrict__ src,
                         const float* __restrict__ tgt, float* __restrict__ cnt,
                         float* __restrict__ ssum, float* __restrict__ tsum,
                         const int* __restrict__ nz, int E, int N) {
    int e = blockIdx.x * blockDim.x + threadIdx.x;
    if (e >= E) return;
    int is64 = (*nz == 0);
    int d = load_idx(ei, e, is64);
    int n = load_idx(ei, (long long)E + e, is64);
    if ((unsigned)d >= (unsigned)N || (unsigned)n >= (unsigned)N) return;
    atomicAdd(&cnt[d], 1.0f);
    atomicAdd(&ssum[3 * d + 0], src[3 * n + 0]);
    atomicAdd(&ssum[3 * d + 1], src[3 * n + 1]);
    atomicAdd(&ssum[3 * d + 2], src[3 * n + 2]);
    atomicAdd(&tsum[3 * d + 0], tgt[3 * n + 0]);
    atomicAdd(&tsum[3 * d + 1], tgt[3 * n + 1]);
    atomicAdd(&tsum[3 * d + 2], tgt[3 * n + 2]);
}

__global__ void k_centers(float* __restrict__ cnt, float* __restrict__ ssum,
                          float* __restrict__ tsum, int N) {
    int i = blockIdx.x * blockDim.x + threadIdx.x;
    if (i >= N) return;
    float inv = 1.0f / fmaxf(cnt[i], 1.0f);
    ssum[3 * i + 0] *= inv; ssum[3 * i + 1] *= inv; ssum[3 * i + 2] *= inv;
    tsum[3 * i + 0] *= inv; tsum[3 * i + 1] *= inv; tsum[3 * i + 2] *= inv;
}

__global__ void k_accum2(const void* __restrict__ ei, const float* __restrict__ src,
                         const float* __restrict__ tgt, const float* __restrict__ ew,
                         const float* __restrict__ sc, const float* __restrict__ tc,
                         float* __restrict__ Mm, const int* __restrict__ nz, int E, int N) {
    int e = blockIdx.x * blockDim.x + threadIdx.x;
    if (e >= E) return;
    int is64 = (*nz == 0);
    int d = load_idx(ei, e, is64);
    int n = load_idx(ei, (long long)E + e, is64);
    if ((unsigned)d >= (unsigned)N || (unsigned)n >= (unsigned)N) return;
    float w = ew[e];
    float a0 = (src[3 * n + 0] - sc[3 * d + 0]) * w;
    float a1 = (src[3 * n + 1] - sc[3 * d + 1]) * w;
    float a2 = (src[3 * n + 2] - sc[3 * d + 2]) * w;
    float b0 = tgt[3 * n + 0] - tc[3 * d + 0];
    float b1 = tgt[3 * n + 1] - tc[3 * d + 1];
    float b2 = tgt[3 * n + 2] - tc[3 * d + 2];
    float* Md = Mm + 9 * (long long)d;
    atomicAdd(Md + 0, a0 * b0); atomicAdd(Md + 1, a0 * b1); atomicAdd(Md + 2, a0 * b2);
    atomicAdd(Md + 3, a1 * b0); atomicAdd(Md + 4, a1 * b1); atomicAdd(Md + 5, a1 * b2);
    atomicAdd(Md + 6, a2 * b0); atomicAdd(Md + 7, a2 * b1); atomicAdd(Md + 8, a2 * b2);
}

__global__ void k_kabsch(const float* __restrict__ Mm, const float* __restrict__ sc,
                         const float* __restrict__ tc, float* __restrict__ Rout,
                         float* __restrict__ Tout, int N) {
    int i = blockIdx.x * blockDim.x + threadIdx.x;
    if (i >= N) return;
    double M[3][3];
#pragma unroll
    for (int r = 0; r < 3; ++r)
#pragma unroll
        for (int c = 0; c < 3; ++c)
            M[r][c] = (double)Mm[9 * (long long)i + 3 * r + c];
    double Rm[3][3];
    kabsch_from_M(M, Rm);
    double s0 = sc[3 * i + 0], s1 = sc[3 * i + 1], s2 = sc[3 * i + 2];
    double t0 = tc[3 * i + 0], t1 = tc[3 * i + 1], t2 = tc[3 * i + 2];
#pragma unroll
    for (int r = 0; r < 3; ++r)
#pragma unroll
        for (int c = 0; c < 3; ++c)
            Rout[9 * (long long)i + 3 * r + c] = (float)Rm[r][c];
    Tout[3 * i + 0] = (float)(t0 - (Rm[0][0] * s0 + Rm[0][1] * s1 + Rm[0][2] * s2));
    Tout[3 * i + 1] = (float)(t1 - (Rm[1][0] * s0 + Rm[1][1] * s1 + Rm[1][2] * s2));
    Tout[3 * i + 2] = (float)(t2 - (Rm[2][0] * s0 + Rm[2][1] * s1 + Rm[2][2] * s2));
}

__global__ void k_weights_plain(const void* __restrict__ ei,
                                const float* __restrict__ src,
                                const float* __restrict__ tgt,
                                const float* __restrict__ R,
                                const float* __restrict__ T,
                                float* __restrict__ wout,
                                const int* __restrict__ nz, int E, int N) {
    int e = blockIdx.x * blockDim.x + threadIdx.x;
    if (e >= E) return;
    int is64 = (*nz == 0);
    int n = load_idx(ei, (long long)E + e, is64);
    float w = 1.0f;
    if ((unsigned)n < (unsigned)N) {
        float p0 = src[3 * n + 0], p1 = src[3 * n + 1], p2 = src[3 * n + 2];
        float q0 = tgt[3 * n + 0], q1 = tgt[3 * n + 1], q2 = tgt[3 * n + 2];
        const float* Rn = R + 9 * (long long)n;
        const float* Tn = T + 3 * (long long)n;
        float x0 = Rn[0] * p0 + Rn[1] * p1 + Rn[2] * p2 + Tn[0];
        float x1 = Rn[3] * p0 + Rn[4] * p1 + Rn[5] * p2 + Tn[1];
        float x2 = Rn[6] * p0 + Rn[7] * p1 + Rn[8] * p2 + Tn[2];
        float d0 = x0 - q0, d1 = x1 - q1, d2 = x2 - q2;
        float dd = d0 * d0 + d1 * d1 + d2 * d2;
        w = kSigma2 / (dd + kSigma2);
    }
    wout[e] = w;
}

extern "C" void kernel_launch(void* const* d_in, const int* in_sizes, int n_in,
                              void* d_out, int out_size, void* d_ws, size_t ws_size,
                              hipStream_t stream) {
    const float* src = (const float*)d_in[0];
    const float* tgt = (const float*)d_in[1];
    const void* ei = d_in[2];
    const float* ew = (const float*)d_in[3];
    int N = in_sizes[0] / 3;
    int E = in_sizes[3];

    float* out = (float*)d_out;
    float* Rout = out;
    float* Tout = out + (size_t)9 * N;
    float* Wout = out + (size_t)12 * N;

    int eb = (E + 255) / 256;
    int nb = (N + 255) / 256;
    int nbuckets = (N + 63) / 64;            // 64-node fine buckets
    int ncoarse = (nbuckets + 127) / 128;    // 8192-node coarse buckets
    int tiles = (int)(((long long)E + 2047) / 2048);
    int ntiles4 = (int)(((long long)E + 4095) / 4096);
    int wb8 = (int)(((long long)E + 2047) / 2048);

    // ws layout: [nz(16) | btot(2048) | cur16 | curC16(256) | boff |
    //             ccnt(ntiles4*16) | cbase(ntiles4*16) | thist(ntiles4*2048) | pad4 |
    //             sedge1 (E int2) | [sedge2 (E int2)] | pt(2(N+1) float4) | wnode(N) | momG(23N)]
    size_t ctrl_ints = 16 + 2048 + (size_t)nbuckets * 16 + 256
                     + (size_t)(nbuckets + 1) + (size_t)ntiles4 * 16 * 2
                     + (size_t)ntiles4 * 2048;
    ctrl_ints = (ctrl_ints + 3) & ~(size_t)3;
    size_t after1 = ctrl_ints + 2 * (size_t)E;
    after1 = (after1 + 3) & ~(size_t)3;
    size_t after2 = after1 + 2 * (size_t)E;
    after2 = (after2 + 3) & ~(size_t)3;
    size_t tail_ints = 8 * (size_t)(N + 1) + (size_t)N + 23 * (size_t)N;
    size_t needA = (after2 + tail_ints) * sizeof(int);
    size_t needB = (after1 + tail_ints) * sizeof(int);

    if (N <= 131072 && nbuckets <= 2048 && ws_size >= needB) {
        int twolevel = (ws_size >= needA) ? 1 : 0;
        int* nz = (int*)d_ws;
        int* btot = nz + 16;
        int* cur16 = btot + 2048;
        int* curC16 = cur16 + (size_t)nbuckets * 16;
        int* boff = curC16 + 256;
        int* ccnt = boff + (nbuckets + 1);
        int* cbase = ccnt + (size_t)ntiles4 * 16;
        int* thist = cbase + (size_t)ntiles4 * 16;
        int2* sedge1 = (int2*)((int*)d_ws + ctrl_ints);
        size_t tail_base = twolevel ? after2 : after1;
        int2* sedge2 = twolevel ? (int2*)((int*)d_ws + after1) : sedge1;
        float4* pt = (float4*)((int*)d_ws + tail_base);
        float* wnode = (float*)(pt + 2 * (size_t)(N + 1));
        float* momG = wnode + N;

        // only nz needs zeroing: thist/btot/ccnt/cbase/boff/cur16 are fully
        // (over)written each iteration by their producer kernels.
        hipMemsetAsync(d_ws, 0, 16 * sizeof(int), stream);

        k_pack<<<nb, 256, 0, stream>>>(src, tgt, pt, N, (const int*)ei, E, nz);
        k_bhist<<<ntiles4, 256, 0, stream>>>(ei, thist, ccnt, nz, E, N, nbuckets, ntiles4);
        k_bsum<<<128, 256, 0, stream>>>(thist, btot, ntiles4);
        k_scan<<<1, 1024, 0, stream>>>(btot, boff, cur16, ccnt, cbase,
                                       nbuckets, ntiles4, ncoarse);
        if (twolevel) {
            k_cscatter<<<ntiles4, 256, 0, stream>>>(ei, ew, cbase, sedge1, nz, E, N, ncoarse);
            k_fscatter<<<ntiles4, 256, 0, stream>>>(sedge1, cur16, boff, sedge2, E, nbuckets, ncoarse);
        } else {
            k_binscatter<<<tiles, 256, 0, stream>>>(ei, ew, cur16, sedge2, nz, E, N, nbuckets);
        }
        k_sortmoment<<<nbuckets, 256, 0, stream>>>(boff, sedge2, pt, momG, N);
        k_kabsch2<<<nb, 256, 0, stream>>>(momG, pt, Rout, Tout, wnode, N);
        k_wgather<<<wb8, 256, 0, stream>>>(ei, wnode, Wout, nz, E, N);
    } else {
        // fallback: atomic path
        float* cnt = (float*)d_ws;
        float* ssum = cnt + N;
        float* tsum = ssum + 3 * (size_t)N;
        float* Mm = tsum + 3 * (size_t)N;
        int* nz = (int*)(Mm + 9 * (size_t)N);
        size_t ws_bytes = (size_t)16 * N * sizeof(float) + 16;
        hipMemsetAsync(d_ws, 0, ws_bytes, stream);
        k_detect<<<1, 256, 0, stream>>>((const int*)ei, E, nz);
        k_accum1<<<eb, 256, 0, stream>>>(ei, src, tgt, cnt, ssum, tsum, nz, E, N);
        k_centers<<<nb, 256, 0, stream>>>(cnt, ssum, tsum, N);
        k_accum2<<<eb, 256, 0, stream>>>(ei, src, tgt, ew, ssum, tsum, Mm, nz, E, N);
        k_kabsch<<<nb, 256, 0, stream>>>(Mm, ssum, tsum, Rout, Tout, N);
        k_weights_plain<<<eb, 256, 0, stream>>>(ei, src, tgt, Rout, Tout, Wout, nz, E, N);
    }
}